// Round 1
// baseline (640.239 us; speedup 1.0000x reference)
//
#include <hip/hip_runtime.h>
#include <math.h>

#define NPT 8192
#define HWIMG 19200
#define TLOC 12

__device__ __forceinline__ float lrelu(float x) { return x > 0.f ? x : 0.01f * x; }

// ---------------- prep: c4 pack, conv3-weight transpose, g zero, feat gather --
__global__ void k_prep(const float* __restrict__ cloud, const int* __restrict__ choose,
                       const float* __restrict__ img,
                       const float* __restrict__ seg1_w, const float* __restrict__ dis1_w,
                       float* __restrict__ c4, float* __restrict__ w3,
                       float* __restrict__ feat, float* __restrict__ g) {
  int i = blockIdx.x * blockDim.x + threadIdx.x;
  if (i < NPT) {
    float4 v;
    v.x = cloud[i*3+0]; v.y = cloud[i*3+1]; v.z = cloud[i*3+2]; v.w = 0.f;
    ((float4*)c4)[i] = v;
  }
  {
    int j = i - NPT;                       // 2*64*384 = 49152 elems
    if (j >= 0 && j < 2*64*384) {
      int h = j / 24576;
      int r = j - h*24576;
      int o = r / 384;
      int k = r - o*384;
      int t = k >> 7;
      int c = k & 127;
      const float* src = h ? dis1_w : seg1_w;
      w3[j] = src[o*384 + c*3 + t];        // w3[h][o][t*128+c] = w[o][c][t]
    }
  }
  {
    int j = i - (NPT + 49152);
    if (j >= 0 && j < 128) g[j] = 0.f;
  }
  {
    int j = i - (NPT + 49152 + 128);
    if (j >= 0 && j < NPT*32) {
      int n = j >> 5, ch = j & 31;
      feat[j] = img[ch*HWIMG + choose[n]];
    }
  }
}

// ---------------- KNN: wave per point, per-lane sorted top-12, shfl merge -----
__global__ __launch_bounds__(256) void k_knn(const float4* __restrict__ c4,
                                             int* __restrict__ idxo, float* __restrict__ wo) {
  int lane = threadIdx.x & 63;
  int wv = threadIdx.x >> 6;
  int p = blockIdx.x * 4 + wv;
  float4 cp = c4[p];
  float d[TLOC]; int jj[TLOC];
#pragma unroll
  for (int q = 0; q < TLOC; ++q) { d[q] = INFINITY; jj[q] = 0; }
  for (int s = 0; s < NPT/64; ++s) {
    int j = s*64 + lane;
    float4 cj = c4[j];
    float dx = cp.x-cj.x, dy = cp.y-cj.y, dz = cp.z-cj.z;
    float d2 = dx*dx + dy*dy + dz*dz;
    if (d2 < d[TLOC-1]) {
      d[TLOC-1] = d2; jj[TLOC-1] = j;
#pragma unroll
      for (int q = TLOC-1; q > 0; --q) {
        if (d[q] < d[q-1]) {
          float td = d[q]; d[q] = d[q-1]; d[q-1] = td;
          int tj = jj[q]; jj[q] = jj[q-1]; jj[q-1] = tj;
        }
      }
    }
  }
  // 32 extractions of the wave-global min among 64 sorted lists
  float my_d = 0.f; int my_j = 0;
  for (int it = 0; it < 32; ++it) {
    unsigned long long key =
        ((unsigned long long)__float_as_uint(d[0]) << 32) | (unsigned)lane;
#pragma unroll
    for (int o = 1; o < 64; o <<= 1) {
      unsigned long long k2 = __shfl_xor(key, o, 64);
      if (k2 < key) key = k2;
    }
    int wl = (int)(key & 63u);
    float wd = __uint_as_float((unsigned)(key >> 32));
    int wj = __shfl(jj[0], wl, 64);
    if (lane == it) { my_d = wd; my_j = wj; }
    if (lane == wl) {
#pragma unroll
      for (int q = 0; q < TLOC-1; ++q) { d[q] = d[q+1]; jj[q] = jj[q+1]; }
      d[TLOC-1] = INFINITY;
    }
  }
  // softmax over the 32 selected (lanes 0..31): w = softmax(-sqrt(d2))
  float v = -sqrtf(my_d);
  float m = v;
#pragma unroll
  for (int o = 1; o < 32; o <<= 1) m = fmaxf(m, __shfl_xor(m, o, 64));
  float e = expf(v - m);
  float s = e;
#pragma unroll
  for (int o = 1; o < 32; o <<= 1) s += __shfl_xor(s, o, 64);
  if (lane < 32) {
    wo[p*32 + lane] = e / s;
    idxo[p*32 + lane] = my_j;
  }
}

// ---------------- generic tiled fp32 GEMM: C = act(A[M,K] @ W[N,K]^T + b) -----
template<int ACT>
__global__ __launch_bounds__(256) void k_gemm(const float* __restrict__ A,
                                              const float* __restrict__ W,
                                              const float* __restrict__ bias,
                                              float* __restrict__ C,
                                              int M, int N, int K) {
  __shared__ float As[16][64];
  __shared__ float Bs[16][64];
  int tid = threadIdx.x;
  int tx = tid & 15, ty = tid >> 4;
  int m0 = blockIdx.x * 64, n0 = blockIdx.y * 64;
  float acc[4][4] = {{0.f}};
  for (int kc = 0; kc < K; kc += 16) {
#pragma unroll
    for (int i = 0; i < 4; ++i) {
      int lin = i*256 + tid;
      int mm = lin >> 4, kk = lin & 15;
      int kg = kc + kk;
      As[kk][mm] = (kg < K) ? A[(size_t)(m0+mm)*K + kg] : 0.f;
      Bs[kk][mm] = (kg < K && (n0+mm) < N) ? W[(size_t)(n0+mm)*K + kg] : 0.f;
    }
    __syncthreads();
#pragma unroll
    for (int k = 0; k < 16; ++k) {
      float a[4], b[4];
#pragma unroll
      for (int i = 0; i < 4; ++i) a[i] = As[k][ty*4+i];
#pragma unroll
      for (int i = 0; i < 4; ++i) b[i] = Bs[k][tx*4+i];
#pragma unroll
      for (int i = 0; i < 4; ++i)
#pragma unroll
        for (int j = 0; j < 4; ++j)
          acc[i][j] += a[i]*b[j];
    }
    __syncthreads();
  }
#pragma unroll
  for (int i = 0; i < 4; ++i) {
    int mm = m0 + ty*4 + i;
#pragma unroll
    for (int j = 0; j < 4; ++j) {
      int nn = n0 + tx*4 + j;
      if (nn < N) {
        float v = acc[i][j] + bias[nn];
        if (ACT) v = lrelu(v);
        C[(size_t)mm*N + nn] = v;
      }
    }
  }
}

// ---------------- pool: weighted max over 32 neighbors + build final[416] -----
__global__ __launch_bounds__(256) void k_pool(const float* __restrict__ Yf,
                                              const float* __restrict__ Yfp,
                                              const float* __restrict__ feat,
                                              const float* __restrict__ pf,
                                              const int* __restrict__ idx,
                                              const float* __restrict__ w,
                                              float* __restrict__ fin) {
  int n = blockIdx.x;
  int tid = threadIdx.x;
  __shared__ int sj[32];
  __shared__ float sw[32];
  if (tid < 32) { sj[tid] = idx[n*32+tid]; sw[tid] = w[n*32+tid]; }
  __syncthreads();
  if (tid < 128) {
    int c = tid;
    float acc = -INFINITY;
#pragma unroll 8
    for (int k = 0; k < 32; ++k) acc = fmaxf(acc, sw[k] * Yfp[(size_t)sj[k]*128 + c]);
    fin[(size_t)n*416 + c] = lrelu(acc);                 // fp  [0,128)
    fin[(size_t)n*416 + 288 + c] = lrelu(pf[n*128 + c]); // pf  [288,416)
    if (c < 32) fin[(size_t)n*416 + 128 + c] = lrelu(feat[n*32 + c]); // feat [128,160)
  } else {
    int c = tid - 128;
    float acc = -INFINITY;
#pragma unroll 8
    for (int k = 0; k < 32; ++k) acc = fmaxf(acc, sw[k] * Yf[(size_t)sj[k]*128 + c]);
    fin[(size_t)n*416 + 160 + c] = lrelu(acc);           // f   [160,288)
  }
}

// ---------------- im2col for conv3 (K=384 rows) -------------------------------
__global__ void k_a3(const float* __restrict__ fused, float* __restrict__ a3) {
  int n = blockIdx.x;
  int k = threadIdx.x;          // 384 threads
  int t = k >> 7, c = k & 127;
  int ns = n + t - 1;
  a3[(size_t)n*384 + k] = (ns >= 0 && ns < NPT) ? fused[(size_t)ns*128 + c] : 0.f;
}

// ---------------- head final 32 -> 1 ------------------------------------------
__global__ __launch_bounds__(256) void k_head3(const float* __restrict__ t2,
                                               const float* __restrict__ w3,
                                               const float* __restrict__ b3,
                                               float* __restrict__ outp) {
  int tid = threadIdx.x;
  int l = tid & 31;
  int n = blockIdx.x*8 + (tid >> 5);
  float v = t2[(size_t)n*32 + l] * w3[l];
#pragma unroll
  for (int o = 1; o < 32; o <<= 1) v += __shfl_xor(v, o, 64);
  if (l == 0) outp[n] = v + b3[0];
}

// ---------------- dis_center softmax ------------------------------------------
__global__ __launch_bounds__(1024) void k_discenter(const float* __restrict__ cloud,
                                                    const float* __restrict__ tvec,
                                                    float* __restrict__ dc) {
  __shared__ float sred[16];
  __shared__ float sbc[2];
  int tid = threadIdx.x;
  float tx = tvec[0], ty = tvec[1], tz = tvec[2];
  float v[8];
#pragma unroll
  for (int i = 0; i < 8; ++i) {
    int n = i*1024 + tid;
    float ax = cloud[n*3+0] + tx, ay = cloud[n*3+1] + ty, az = cloud[n*3+2] + tz;
    v[i] = sqrtf(ax*ax + ay*ay + az*az);
  }
  float m = v[0];
#pragma unroll
  for (int i = 1; i < 8; ++i) m = fmaxf(m, v[i]);
#pragma unroll
  for (int o = 1; o < 64; o <<= 1) m = fmaxf(m, __shfl_xor(m, o, 64));
  if ((tid & 63) == 0) sred[tid >> 6] = m;
  __syncthreads();
  if (tid == 0) {
    float mm = sred[0];
    for (int i = 1; i < 16; ++i) mm = fmaxf(mm, sred[i]);
    sbc[0] = mm;
  }
  __syncthreads();
  float gm = sbc[0];
  float e[8]; float s = 0.f;
#pragma unroll
  for (int i = 0; i < 8; ++i) { e[i] = expf(v[i] - gm); s += e[i]; }
#pragma unroll
  for (int o = 1; o < 64; o <<= 1) s += __shfl_xor(s, o, 64);
  __syncthreads();
  if ((tid & 63) == 0) sred[tid >> 6] = s;
  __syncthreads();
  if (tid == 0) {
    float ss = 0.f;
    for (int i = 0; i < 16; ++i) ss += sred[i];
    sbc[1] = ss;
  }
  __syncthreads();
  float gs = sbc[1];
#pragma unroll
  for (int i = 0; i < 8; ++i) dc[i*1024 + tid] = e[i] / gs;
}

// ---------------- g = sum_n fused[n]*dc[n]*seg[n] ------------------------------
__global__ __launch_bounds__(256) void k_g(const float* __restrict__ fused,
                                           const float* __restrict__ dc,
                                           const float* __restrict__ seg,
                                           float* __restrict__ g) {
  __shared__ float sbuf[256];
  int tid = threadIdx.x;
  int c = tid & 127, h = tid >> 7;
  float acc = 0.f;
  for (int r = 0; r < 128; ++r) {
    int n = blockIdx.x*256 + r*2 + h;
    acc += fused[(size_t)n*128 + c] * dc[n] * seg[n];
  }
  sbuf[tid] = acc;
  __syncthreads();
  if (tid < 128) atomicAdd(&g[c], sbuf[tid] + sbuf[tid+128]);
}

// ---------------- keypoint MLP 128->90->64->24 ---------------------------------
__global__ __launch_bounds__(128) void k_kp(const float* __restrict__ g,
                                            const float* __restrict__ l1w, const float* __restrict__ l1b,
                                            const float* __restrict__ l2w, const float* __restrict__ l2b,
                                            const float* __restrict__ l3w, const float* __restrict__ l3b,
                                            float* __restrict__ outp) {
  __shared__ float sg[128], s1[90], s2[64];
  int tid = threadIdx.x;
  sg[tid] = g[tid];
  __syncthreads();
  if (tid < 90) {
    float a = l1b[tid];
    for (int i = 0; i < 128; ++i) a += sg[i]*l1w[tid*128+i];
    s1[tid] = lrelu(a);
  }
  __syncthreads();
  if (tid < 64) {
    float a = l2b[tid];
    for (int i = 0; i < 90; ++i) a += s1[i]*l2w[tid*90+i];
    s2[tid] = lrelu(a);
  }
  __syncthreads();
  if (tid < 24) {
    float a = l3b[tid];
    for (int i = 0; i < 64; ++i) a += s2[i]*l3w[tid*64+i];
    outp[tid] = a;
  }
}

extern "C" void kernel_launch(void* const* d_in, const int* in_sizes, int n_in,
                              void* d_out, int out_size, void* d_ws, size_t ws_size,
                              hipStream_t stream) {
  const float* seg      = (const float*)d_in[0];
  const float* img      = (const float*)d_in[1];
  const float* cloud    = (const float*)d_in[2];
  const float* tvec     = (const float*)d_in[3];
  const int*   choose   = (const int*)d_in[4];
  const float* pconv1_w = (const float*)d_in[5];
  const float* pconv1_b = (const float*)d_in[6];
  const float* pconv2_w = (const float*)d_in[7];
  const float* pconv2_b = (const float*)d_in[8];
  const float* conv1_w  = (const float*)d_in[9];
  const float* conv1_b  = (const float*)d_in[10];
  const float* conv2_w  = (const float*)d_in[11];
  const float* conv2_b  = (const float*)d_in[12];
  const float* psconv1_w= (const float*)d_in[13];
  const float* psconv1_b= (const float*)d_in[14];
  const float* psconv2_w= (const float*)d_in[15];
  const float* psconv2_b= (const float*)d_in[16];
  const float* final_w  = (const float*)d_in[17];
  const float* final_b  = (const float*)d_in[18];
  const float* seg1_w   = (const float*)d_in[19];
  const float* seg1_b   = (const float*)d_in[20];
  const float* seg2_w   = (const float*)d_in[21];
  const float* seg2_b   = (const float*)d_in[22];
  const float* seg3_w   = (const float*)d_in[23];
  const float* seg3_b   = (const float*)d_in[24];
  const float* dis1_w   = (const float*)d_in[25];
  const float* dis1_b   = (const float*)d_in[26];
  const float* dis2_w   = (const float*)d_in[27];
  const float* dis2_b   = (const float*)d_in[28];
  const float* dis3_w   = (const float*)d_in[29];
  const float* dis3_b   = (const float*)d_in[30];
  const float* lin1_w   = (const float*)d_in[31];
  const float* lin1_b   = (const float*)d_in[32];
  const float* lin2_w   = (const float*)d_in[33];
  const float* lin2_b   = (const float*)d_in[34];
  const float* lin3_w   = (const float*)d_in[35];
  const float* lin3_b   = (const float*)d_in[36];

  float* out = (float*)d_out;
  float* ws  = (float*)d_ws;

  // workspace layout (floats), with dead-region aliasing
  float* c4    = ws + 0;         // 32768
  float* feat  = ws + 32768;     // 262144
  float* h1    = ws + 294912;    // 524288
  float* pf    = ws + 819200;    // 1048576
  float* yh    = ws + 1867776;   // 524288
  float* Yf    = ws + 2392064;   // 1048576  (aliased later by t2s/t2d)
  float* ph    = ws + 3440640;   // 2097152  (aliased later by t1s/t1d)
  float* Yfp   = ws + 5537792;   // 1048576
  int*   idx   = (int*)(ws + 6586368);  // 262144
  float* wsm   = ws + 6848512;   // 262144
  float* fin   = ws + 7110656;   // 3407872  (aliased later by a3: 3145728)
  float* fused = ws + 10518528;  // 1048576
  float* w3    = ws + 11567104;  // 49152 (seg then dis)
  float* g     = ws + 11616256;  // 128
  float* t1s   = ph;
  float* t1d   = ph + 524288;
  float* t2s   = Yf;
  float* t2d   = Yf + 262144;
  float* a3    = fin;
  float* w3seg = w3;
  float* w3dis = w3 + 24576;

  float* o_kp   = out;            // 24
  float* o_disp = out + 24;       // 8192
  float* o_dc   = out + 8216;     // 8192
  float* o_segp = out + 16408;    // 8192

  k_prep<<<1249, 256, 0, stream>>>(cloud, choose, img, seg1_w, dis1_w, c4, w3, feat, g);

  // point MLP: cloud -> h1 -> pf
  k_gemm<1><<<dim3(128,1), 256, 0, stream>>>(cloud, pconv1_w, pconv1_b, h1, NPT, 64, 3);
  k_gemm<0><<<dim3(128,2), 256, 0, stream>>>(h1, pconv2_w, pconv2_b, pf, NPT, 128, 64);

  k_knn<<<2048, 256, 0, stream>>>((const float4*)c4, idx, wsm);

  // per-point MLPs (gather-commuted)
  k_gemm<1><<<dim3(128,1), 256, 0, stream>>>(feat, conv1_w, conv1_b, yh, NPT, 64, 32);
  k_gemm<0><<<dim3(128,2), 256, 0, stream>>>(yh, conv2_w, conv2_b, Yf, NPT, 128, 64);
  k_gemm<1><<<dim3(128,4), 256, 0, stream>>>(pf, psconv1_w, psconv1_b, ph, NPT, 256, 128);
  k_gemm<0><<<dim3(128,2), 256, 0, stream>>>(ph, psconv2_w, psconv2_b, Yfp, NPT, 128, 256);

  k_pool<<<NPT, 256, 0, stream>>>(Yf, Yfp, feat, pf, idx, wsm, fin);

  k_gemm<0><<<dim3(128,2), 256, 0, stream>>>(fin, final_w, final_b, fused, NPT, 128, 416);

  k_a3<<<NPT, 384, 0, stream>>>(fused, a3);

  k_gemm<1><<<dim3(128,1), 256, 0, stream>>>(a3, w3seg, seg1_b, t1s, NPT, 64, 384);
  k_gemm<1><<<dim3(128,1), 256, 0, stream>>>(a3, w3dis, dis1_b, t1d, NPT, 64, 384);
  k_gemm<1><<<dim3(128,1), 256, 0, stream>>>(t1s, seg2_w, seg2_b, t2s, NPT, 32, 64);
  k_gemm<1><<<dim3(128,1), 256, 0, stream>>>(t1d, dis2_w, dis2_b, t2d, NPT, 32, 64);

  k_head3<<<1024, 256, 0, stream>>>(t2s, seg3_w, seg3_b, o_segp);
  k_head3<<<1024, 256, 0, stream>>>(t2d, dis3_w, dis3_b, o_disp);

  k_discenter<<<1, 1024, 0, stream>>>(cloud, tvec, o_dc);

  k_g<<<32, 256, 0, stream>>>(fused, o_dc, seg, g);
  k_kp<<<1, 128, 0, stream>>>(g, lin1_w, lin1_b, lin2_w, lin2_b, lin3_w, lin3_b, o_kp);

  (void)in_sizes; (void)n_in; (void)out_size; (void)ws_size;
}

// Round 2
// 539.560 us; speedup vs baseline: 1.1866x; 1.1866x over previous
//
#include <hip/hip_runtime.h>
#include <math.h>

#define NPT 8192
#define HWIMG 19200
#define KCAP 256

__device__ __forceinline__ float lrelu(float x) { return x > 0.f ? x : 0.01f * x; }

// ---------------- prep: c4 pack, conv3-weight transpose, merged head tables ---
__global__ void k_prep(const float* __restrict__ cloud, const int* __restrict__ choose,
                       const float* __restrict__ img,
                       const float* __restrict__ seg1_w, const float* __restrict__ dis1_w,
                       const float* __restrict__ seg1_b, const float* __restrict__ dis1_b,
                       const float* __restrict__ seg2_w, const float* __restrict__ dis2_w,
                       const float* __restrict__ seg2_b, const float* __restrict__ dis2_b,
                       float* __restrict__ c4, float* __restrict__ w3,
                       float* __restrict__ biasc, float* __restrict__ W2p,
                       float* __restrict__ bias2c,
                       float* __restrict__ feat, float* __restrict__ g) {
  int i = blockIdx.x * blockDim.x + threadIdx.x;
  if (i < NPT) {
    float4 v;
    v.x = cloud[i*3+0]; v.y = cloud[i*3+1]; v.z = cloud[i*3+2]; v.w = 0.f;
    ((float4*)c4)[i] = v;
  }
  {
    int j = i - NPT;                       // 2*64*384 = 49152 elems
    if (j >= 0 && j < 2*64*384) {
      int h = j / 24576;
      int r = j - h*24576;
      int o = r / 384;
      int k = r - o*384;
      int t = k >> 7;
      int c = k & 127;
      const float* src = h ? dis1_w : seg1_w;
      w3[j] = src[o*384 + c*3 + t];        // w3[h][o][t*128+c] = w[o][c][t]
    }
  }
  {
    int j = i - (NPT + 49152);
    if (j >= 0 && j < 128) biasc[j] = (j < 64) ? seg1_b[j] : dis1_b[j-64];
  }
  {
    int j = i - (NPT + 49152 + 128);
    if (j >= 0 && j < 8192) {              // W2p[64][128] block-diagonal
      int o = j >> 7, c = j & 127;
      float v = 0.f;
      if (o < 32) { if (c < 64) v = seg2_w[o*64 + c]; }
      else        { if (c >= 64) v = dis2_w[(o-32)*64 + (c-64)]; }
      W2p[j] = v;
    }
  }
  {
    int j = i - (NPT + 49152 + 128 + 8192);
    if (j >= 0 && j < 64) bias2c[j] = (j < 32) ? seg2_b[j] : dis2_b[j-32];
  }
  {
    int j = i - (NPT + 49152 + 128 + 8192 + 64);
    if (j >= 0 && j < 128) g[j] = 0.f;
  }
  {
    int j = i - (NPT + 49152 + 128 + 8192 + 64 + 128);
    if (j >= 0 && j < NPT*32) {
      int n = j >> 5, ch = j & 31;
      feat[j] = img[ch*HWIMG + choose[n]];
    }
  }
}

// ---------------- KNN via threshold prune: block = 2 queries -------------------
// T_ub = 32nd smallest of 256 per-thread mins >= true 32nd-NN distance (each of
// the 32 threads with smallest mins witnesses a distinct candidate <= T_ub).
__global__ __launch_bounds__(256) void k_knn(const float4* __restrict__ c4,
                                             int* __restrict__ idxo, float* __restrict__ wo) {
  __shared__ float smin[2][256];
  __shared__ float sd[2][KCAP];
  __shared__ int   sj[2][KCAP];
  __shared__ float sT[2];
  __shared__ int   scnt[2];
  int tid = threadIdx.x;
  int lane = tid & 63, wv = tid >> 6;
  int q0 = blockIdx.x * 2;
  float4 p0 = c4[q0], p1 = c4[q0 + 1];
  float d0[32], d1[32];
  float m0 = INFINITY, m1 = INFINITY;
#pragma unroll
  for (int t = 0; t < 32; ++t) {
    float4 cj = c4[t*256 + tid];
    float ax = p0.x-cj.x, ay = p0.y-cj.y, az = p0.z-cj.z;
    float bx = p1.x-cj.x, by = p1.y-cj.y, bz = p1.z-cj.z;
    d0[t] = ax*ax + ay*ay + az*az;
    d1[t] = bx*bx + by*by + bz*bz;
    m0 = fminf(m0, d0[t]);
    m1 = fminf(m1, d1[t]);
  }
  smin[0][tid] = m0;
  smin[1][tid] = m1;
  if (tid < 2) scnt[tid] = 0;
  __syncthreads();
  // waves 0,1: T_ub = 32nd smallest of 256 thread-mins
  if (wv < 2) {
    float v0 = smin[wv][lane*4+0], v1 = smin[wv][lane*4+1];
    float v2 = smin[wv][lane*4+2], v3 = smin[wv][lane*4+3];
#define CSV(a,b) { if (b < a) { float t_ = a; a = b; b = t_; } }
    CSV(v0,v2) CSV(v1,v3) CSV(v0,v1) CSV(v2,v3) CSV(v1,v2)
    float T = 0.f;
    for (int it = 0; it < 32; ++it) {
      unsigned long long key =
          ((unsigned long long)__float_as_uint(v0) << 32) | (unsigned)lane;
#pragma unroll
      for (int o = 1; o < 64; o <<= 1) {
        unsigned long long k2 = __shfl_xor(key, o, 64);
        if (k2 < key) key = k2;
      }
      int wl = (int)(key & 63u);
      T = __uint_as_float((unsigned)(key >> 32));
      if (lane == wl) { v0 = v1; v1 = v2; v2 = v3; v3 = INFINITY; }
    }
    if (lane == 0) sT[wv] = T;
  }
  __syncthreads();
  float T0 = sT[0], T1 = sT[1];
#pragma unroll
  for (int t = 0; t < 32; ++t) {
    int j = t*256 + tid;
    if (d0[t] <= T0) {
      int p = atomicAdd(&scnt[0], 1);
      if (p < KCAP) { sd[0][p] = d0[t]; sj[0][p] = j; }
    }
    if (d1[t] <= T1) {
      int p = atomicAdd(&scnt[1], 1);
      if (p < KCAP) { sd[1][p] = d1[t]; sj[1][p] = j; }
    }
  }
  __syncthreads();
  // waves 0,1: exact top-32 among survivors (>=32 guaranteed)
  if (wv < 2) {
    int M = scnt[wv]; if (M > KCAP) M = KCAP;
    float f0, f1, f2, f3; int j0, j1, j2, j3;
    f0 = (lane      < M) ? sd[wv][lane      ] : INFINITY; j0 = (lane      < M) ? sj[wv][lane      ] : 0;
    f1 = (lane+ 64  < M) ? sd[wv][lane+ 64  ] : INFINITY; j1 = (lane+ 64  < M) ? sj[wv][lane+ 64  ] : 0;
    f2 = (lane+128  < M) ? sd[wv][lane+128  ] : INFINITY; j2 = (lane+128  < M) ? sj[wv][lane+128  ] : 0;
    f3 = (lane+192  < M) ? sd[wv][lane+192  ] : INFINITY; j3 = (lane+192  < M) ? sj[wv][lane+192  ] : 0;
#define CSP(a,b,ja,jb) { if (b < a) { float t_ = a; a = b; b = t_; int u_ = ja; ja = jb; jb = u_; } }
    CSP(f0,f2,j0,j2) CSP(f1,f3,j1,j3) CSP(f0,f1,j0,j1) CSP(f2,f3,j2,j3) CSP(f1,f2,j1,j2)
    float my_d = 0.f; int my_j = 0;
    for (int it = 0; it < 32; ++it) {
      unsigned long long key =
          ((unsigned long long)__float_as_uint(f0) << 32) | (unsigned)lane;
#pragma unroll
      for (int o = 1; o < 64; o <<= 1) {
        unsigned long long k2 = __shfl_xor(key, o, 64);
        if (k2 < key) key = k2;
      }
      int wl = (int)(key & 63u);
      float wd = __uint_as_float((unsigned)(key >> 32));
      int wj = __shfl(j0, wl, 64);
      if (lane == it) { my_d = wd; my_j = wj; }
      if (lane == wl) { f0 = f1; f1 = f2; f2 = f3; f3 = INFINITY; j0 = j1; j1 = j2; j2 = j3; }
    }
    // softmax over the 32 selected: w = softmax(-sqrt(d2))
    float v = -sqrtf(my_d);
    float mx = v;
#pragma unroll
    for (int o = 1; o < 32; o <<= 1) mx = fmaxf(mx, __shfl_xor(mx, o, 32));
    float e = expf(v - mx);
    float s = e;
#pragma unroll
    for (int o = 1; o < 32; o <<= 1) s += __shfl_xor(s, o, 32);
    if (lane < 32) {
      int q = q0 + wv;
      wo[q*32 + lane] = e / s;
      idxo[q*32 + lane] = my_j;
    }
  }
}

// ---------------- tiled fp32 GEMM: C = act(A[M,K] @ W[N,K]^T + b), float4 LDS --
template<int ACT>
__global__ __launch_bounds__(256) void k_gemm(const float* __restrict__ A,
                                              const float* __restrict__ W,
                                              const float* __restrict__ bias,
                                              float* __restrict__ C,
                                              int M, int N, int K) {
  __shared__ float As[16][64];
  __shared__ float Bs[16][64];
  int tid = threadIdx.x;
  int tx = tid & 15, ty = tid >> 4;
  int m0 = blockIdx.x * 64, n0 = blockIdx.y * 64;
  float acc[4][4] = {{0.f}};
  for (int kc = 0; kc < K; kc += 16) {
#pragma unroll
    for (int i = 0; i < 4; ++i) {
      int lin = i*256 + tid;
      int mm = lin >> 4, kk = lin & 15;
      int kg = kc + kk;
      As[kk][mm] = (kg < K) ? A[(size_t)(m0+mm)*K + kg] : 0.f;
      Bs[kk][mm] = (kg < K && (n0+mm) < N) ? W[(size_t)(n0+mm)*K + kg] : 0.f;
    }
    __syncthreads();
#pragma unroll
    for (int k = 0; k < 16; ++k) {
      float4 av = *(const float4*)&As[k][ty*4];
      float4 bv = *(const float4*)&Bs[k][tx*4];
      acc[0][0] += av.x*bv.x; acc[0][1] += av.x*bv.y; acc[0][2] += av.x*bv.z; acc[0][3] += av.x*bv.w;
      acc[1][0] += av.y*bv.x; acc[1][1] += av.y*bv.y; acc[1][2] += av.y*bv.z; acc[1][3] += av.y*bv.w;
      acc[2][0] += av.z*bv.x; acc[2][1] += av.z*bv.y; acc[2][2] += av.z*bv.z; acc[2][3] += av.z*bv.w;
      acc[3][0] += av.w*bv.x; acc[3][1] += av.w*bv.y; acc[3][2] += av.w*bv.z; acc[3][3] += av.w*bv.w;
    }
    __syncthreads();
  }
#pragma unroll
  for (int i = 0; i < 4; ++i) {
    int mm = m0 + ty*4 + i;
#pragma unroll
    for (int j = 0; j < 4; ++j) {
      int nn = n0 + tx*4 + j;
      if (nn < N) {
        float v = acc[i][j] + bias[nn];
        if (ACT) v = lrelu(v);
        C[(size_t)mm*N + nn] = v;
      }
    }
  }
}

// ---------------- pool: weighted max over 32 neighbors + build final[416] -----
__global__ __launch_bounds__(256) void k_pool(const float* __restrict__ Yf,
                                              const float* __restrict__ Yfp,
                                              const float* __restrict__ feat,
                                              const float* __restrict__ pf,
                                              const int* __restrict__ idx,
                                              const float* __restrict__ w,
                                              float* __restrict__ fin) {
  int n = blockIdx.x;
  int tid = threadIdx.x;
  __shared__ int sj[32];
  __shared__ float sw[32];
  if (tid < 32) { sj[tid] = idx[n*32+tid]; sw[tid] = w[n*32+tid]; }
  __syncthreads();
  if (tid < 128) {
    int c = tid;
    float acc = -INFINITY;
#pragma unroll 8
    for (int k = 0; k < 32; ++k) acc = fmaxf(acc, sw[k] * Yfp[(size_t)sj[k]*128 + c]);
    fin[(size_t)n*416 + c] = lrelu(acc);                 // fp  [0,128)
    fin[(size_t)n*416 + 288 + c] = lrelu(pf[n*128 + c]); // pf  [288,416)
    if (c < 32) fin[(size_t)n*416 + 128 + c] = lrelu(feat[n*32 + c]); // feat [128,160)
  } else {
    int c = tid - 128;
    float acc = -INFINITY;
#pragma unroll 8
    for (int k = 0; k < 32; ++k) acc = fmaxf(acc, sw[k] * Yf[(size_t)sj[k]*128 + c]);
    fin[(size_t)n*416 + 160 + c] = lrelu(acc);           // f   [160,288)
  }
}

// ---------------- im2col for conv3 (K=384 rows) -------------------------------
__global__ void k_a3(const float* __restrict__ fused, float* __restrict__ a3) {
  int n = blockIdx.x;
  int k = threadIdx.x;          // 384 threads
  int t = k >> 7, c = k & 127;
  int ns = n + t - 1;
  a3[(size_t)n*384 + k] = (ns >= 0 && ns < NPT) ? fused[(size_t)ns*128 + c] : 0.f;
}

// ---------------- paired head final: seg (cols 0..31), dis (cols 32..63) ------
__global__ __launch_bounds__(256) void k_headpair(const float* __restrict__ t2,
                                                  const float* __restrict__ segw, const float* __restrict__ segb,
                                                  const float* __restrict__ disw, const float* __restrict__ disb,
                                                  float* __restrict__ osegp, float* __restrict__ odisp) {
  int tid = threadIdx.x;
  int lane = tid & 63;
  int n = blockIdx.x*4 + (tid >> 6);
  float wv = (lane < 32) ? segw[lane] : disw[lane - 32];
  float v = t2[(size_t)n*64 + lane] * wv;
#pragma unroll
  for (int o = 1; o < 32; o <<= 1) v += __shfl_xor(v, o, 32);
  if (lane == 0)  osegp[n] = v + segb[0];
  if (lane == 32) odisp[n] = v + disb[0];
}

// ---------------- dis_center softmax ------------------------------------------
__global__ __launch_bounds__(1024) void k_discenter(const float* __restrict__ cloud,
                                                    const float* __restrict__ tvec,
                                                    float* __restrict__ dc) {
  __shared__ float sred[16];
  __shared__ float sbc[2];
  int tid = threadIdx.x;
  float tx = tvec[0], ty = tvec[1], tz = tvec[2];
  float v[8];
#pragma unroll
  for (int i = 0; i < 8; ++i) {
    int n = i*1024 + tid;
    float ax = cloud[n*3+0] + tx, ay = cloud[n*3+1] + ty, az = cloud[n*3+2] + tz;
    v[i] = sqrtf(ax*ax + ay*ay + az*az);
  }
  float m = v[0];
#pragma unroll
  for (int i = 1; i < 8; ++i) m = fmaxf(m, v[i]);
#pragma unroll
  for (int o = 1; o < 64; o <<= 1) m = fmaxf(m, __shfl_xor(m, o, 64));
  if ((tid & 63) == 0) sred[tid >> 6] = m;
  __syncthreads();
  if (tid == 0) {
    float mm = sred[0];
    for (int i = 1; i < 16; ++i) mm = fmaxf(mm, sred[i]);
    sbc[0] = mm;
  }
  __syncthreads();
  float gm = sbc[0];
  float e[8]; float s = 0.f;
#pragma unroll
  for (int i = 0; i < 8; ++i) { e[i] = expf(v[i] - gm); s += e[i]; }
#pragma unroll
  for (int o = 1; o < 64; o <<= 1) s += __shfl_xor(s, o, 64);
  __syncthreads();
  if ((tid & 63) == 0) sred[tid >> 6] = s;
  __syncthreads();
  if (tid == 0) {
    float ss = 0.f;
    for (int i = 0; i < 16; ++i) ss += sred[i];
    sbc[1] = ss;
  }
  __syncthreads();
  float gs = sbc[1];
#pragma unroll
  for (int i = 0; i < 8; ++i) dc[i*1024 + tid] = e[i] / gs;
}

// ---------------- g = sum_n fused[n]*dc[n]*seg[n] ------------------------------
__global__ __launch_bounds__(256) void k_g(const float* __restrict__ fused,
                                           const float* __restrict__ dc,
                                           const float* __restrict__ seg,
                                           float* __restrict__ g) {
  __shared__ float sbuf[256];
  int tid = threadIdx.x;
  int c = tid & 127, h = tid >> 7;
  float acc = 0.f;
  for (int r = 0; r < 128; ++r) {
    int n = blockIdx.x*256 + r*2 + h;
    acc += fused[(size_t)n*128 + c] * dc[n] * seg[n];
  }
  sbuf[tid] = acc;
  __syncthreads();
  if (tid < 128) atomicAdd(&g[c], sbuf[tid] + sbuf[tid+128]);
}

// ---------------- keypoint MLP 128->90->64->24 ---------------------------------
__global__ __launch_bounds__(128) void k_kp(const float* __restrict__ g,
                                            const float* __restrict__ l1w, const float* __restrict__ l1b,
                                            const float* __restrict__ l2w, const float* __restrict__ l2b,
                                            const float* __restrict__ l3w, const float* __restrict__ l3b,
                                            float* __restrict__ outp) {
  __shared__ float sg[128], s1[90], s2[64];
  int tid = threadIdx.x;
  sg[tid] = g[tid];
  __syncthreads();
  if (tid < 90) {
    float a = l1b[tid];
    for (int i = 0; i < 128; ++i) a += sg[i]*l1w[tid*128+i];
    s1[tid] = lrelu(a);
  }
  __syncthreads();
  if (tid < 64) {
    float a = l2b[tid];
    for (int i = 0; i < 90; ++i) a += s1[i]*l2w[tid*90+i];
    s2[tid] = lrelu(a);
  }
  __syncthreads();
  if (tid < 24) {
    float a = l3b[tid];
    for (int i = 0; i < 64; ++i) a += s2[i]*l3w[tid*64+i];
    outp[tid] = a;
  }
}

extern "C" void kernel_launch(void* const* d_in, const int* in_sizes, int n_in,
                              void* d_out, int out_size, void* d_ws, size_t ws_size,
                              hipStream_t stream) {
  const float* seg      = (const float*)d_in[0];
  const float* img      = (const float*)d_in[1];
  const float* cloud    = (const float*)d_in[2];
  const float* tvec     = (const float*)d_in[3];
  const int*   choose   = (const int*)d_in[4];
  const float* pconv1_w = (const float*)d_in[5];
  const float* pconv1_b = (const float*)d_in[6];
  const float* pconv2_w = (const float*)d_in[7];
  const float* pconv2_b = (const float*)d_in[8];
  const float* conv1_w  = (const float*)d_in[9];
  const float* conv1_b  = (const float*)d_in[10];
  const float* conv2_w  = (const float*)d_in[11];
  const float* conv2_b  = (const float*)d_in[12];
  const float* psconv1_w= (const float*)d_in[13];
  const float* psconv1_b= (const float*)d_in[14];
  const float* psconv2_w= (const float*)d_in[15];
  const float* psconv2_b= (const float*)d_in[16];
  const float* final_w  = (const float*)d_in[17];
  const float* final_b  = (const float*)d_in[18];
  const float* seg1_w   = (const float*)d_in[19];
  const float* seg1_b   = (const float*)d_in[20];
  const float* seg2_w   = (const float*)d_in[21];
  const float* seg2_b   = (const float*)d_in[22];
  const float* seg3_w   = (const float*)d_in[23];
  const float* seg3_b   = (const float*)d_in[24];
  const float* dis1_w   = (const float*)d_in[25];
  const float* dis1_b   = (const float*)d_in[26];
  const float* dis2_w   = (const float*)d_in[27];
  const float* dis2_b   = (const float*)d_in[28];
  const float* dis3_w   = (const float*)d_in[29];
  const float* dis3_b   = (const float*)d_in[30];
  const float* lin1_w   = (const float*)d_in[31];
  const float* lin1_b   = (const float*)d_in[32];
  const float* lin2_w   = (const float*)d_in[33];
  const float* lin2_b   = (const float*)d_in[34];
  const float* lin3_w   = (const float*)d_in[35];
  const float* lin3_b   = (const float*)d_in[36];

  float* out = (float*)d_out;
  float* ws  = (float*)d_ws;

  // workspace layout (floats), explicit lifetimes + aliasing
  float* c4    = ws + 0;         // 32768
  float* feat  = ws + 32768;     // 262144
  float* h1    = ws + 294912;    // 524288  (reused by yh)
  float* pf    = ws + 819200;    // 1048576
  float* Yf    = ws + 1867776;   // 1048576 (reused by t2sd)
  float* ph    = ws + 2916352;   // 2097152 (reused by t1sd)
  float* Yfp   = ws + 5013504;   // 1048576
  int*   idx   = (int*)(ws + 6062080);  // 262144
  float* wsm   = ws + 6324224;   // 262144
  float* fin   = ws + 6586368;   // 3407872 (reused by a3: 3145728)
  float* fused = ws + 9994240;   // 1048576
  float* w3    = ws + 11042816;  // 49152 (seg then dis)
  float* biasc = ws + 11091968;  // 128
  float* W2p   = ws + 11092096;  // 8192
  float* bias2c= ws + 11100288;  // 64
  float* g     = ws + 11100352;  // 128   -> total 11,100,480 floats (44.4 MB)
  float* yh    = h1;
  float* t1sd  = ph;
  float* t2sd  = Yf;
  float* a3    = fin;

  float* o_kp   = out;            // 24
  float* o_disp = out + 24;       // 8192
  float* o_dc   = out + 8216;     // 8192
  float* o_segp = out + 16408;    // 8192

  k_prep<<<1282, 256, 0, stream>>>(cloud, choose, img, seg1_w, dis1_w,
                                   seg1_b, dis1_b, seg2_w, dis2_w, seg2_b, dis2_b,
                                   c4, w3, biasc, W2p, bias2c, feat, g);

  // point MLP: cloud -> h1 -> pf
  k_gemm<1><<<dim3(128,1), 256, 0, stream>>>(cloud, pconv1_w, pconv1_b, h1, NPT, 64, 3);
  k_gemm<0><<<dim3(128,2), 256, 0, stream>>>(h1, pconv2_w, pconv2_b, pf, NPT, 128, 64);

  k_knn<<<4096, 256, 0, stream>>>((const float4*)c4, idx, wsm);

  // per-point MLPs (gather-commuted)
  k_gemm<1><<<dim3(128,1), 256, 0, stream>>>(feat, conv1_w, conv1_b, yh, NPT, 64, 32);
  k_gemm<0><<<dim3(128,2), 256, 0, stream>>>(yh, conv2_w, conv2_b, Yf, NPT, 128, 64);
  k_gemm<1><<<dim3(128,4), 256, 0, stream>>>(pf, psconv1_w, psconv1_b, ph, NPT, 256, 128);
  k_gemm<0><<<dim3(128,2), 256, 0, stream>>>(ph, psconv2_w, psconv2_b, Yfp, NPT, 128, 256);

  k_pool<<<NPT, 256, 0, stream>>>(Yf, Yfp, feat, pf, idx, wsm, fin);

  k_gemm<0><<<dim3(128,2), 256, 0, stream>>>(fin, final_w, final_b, fused, NPT, 128, 416);

  k_a3<<<NPT, 384, 0, stream>>>(fused, a3);

  // merged seg|dis head chains
  k_gemm<1><<<dim3(128,2), 256, 0, stream>>>(a3, w3, biasc, t1sd, NPT, 128, 384);
  k_gemm<1><<<dim3(128,1), 256, 0, stream>>>(t1sd, W2p, bias2c, t2sd, NPT, 64, 128);
  k_headpair<<<2048, 256, 0, stream>>>(t2sd, seg3_w, seg3_b, dis3_w, dis3_b, o_segp, o_disp);

  k_discenter<<<1, 1024, 0, stream>>>(cloud, tvec, o_dc);

  k_g<<<32, 256, 0, stream>>>(fused, o_dc, seg, g);
  k_kp<<<1, 128, 0, stream>>>(g, lin1_w, lin1_b, lin2_w, lin2_b, lin3_w, lin3_b, o_kp);

  (void)in_sizes; (void)n_in; (void)out_size; (void)ws_size;
}

// Round 3
// 382.908 us; speedup vs baseline: 1.6720x; 1.4091x over previous
//
#include <hip/hip_runtime.h>
#include <math.h>

#define NPT 8192
#define HWIMG 19200
#define KCAP 128

__device__ __forceinline__ float lrelu(float x) { return x > 0.f ? x : 0.01f * x; }

// ---- bitonic helpers: 64-lane sort / merge of u64 keys (ascending) ----------
__device__ __forceinline__ unsigned long long bsort64(unsigned long long key, int lane) {
#pragma unroll
  for (int k = 2; k <= 64; k <<= 1) {
#pragma unroll
    for (int j = k >> 1; j > 0; j >>= 1) {
      unsigned long long o = __shfl_xor(key, j, 64);
      bool keepmin = (((lane & j) == 0) == ((lane & k) == 0));
      bool omin = o < key;
      key = (omin == keepmin) ? o : key;
    }
  }
  return key;
}
__device__ __forceinline__ unsigned long long bmerge64(unsigned long long key, int lane) {
#pragma unroll
  for (int j = 32; j > 0; j >>= 1) {
    unsigned long long o = __shfl_xor(key, j, 64);
    bool keepmin = ((lane & j) == 0);
    bool omin = o < key;
    key = (omin == keepmin) ? o : key;
  }
  return key;
}

// ---------------- prep: c4 pack, conv3-weight transpose, merged head tables ---
__global__ void k_prep(const float* __restrict__ cloud, const int* __restrict__ choose,
                       const float* __restrict__ img,
                       const float* __restrict__ seg1_w, const float* __restrict__ dis1_w,
                       const float* __restrict__ seg1_b, const float* __restrict__ dis1_b,
                       const float* __restrict__ seg2_w, const float* __restrict__ dis2_w,
                       const float* __restrict__ seg2_b, const float* __restrict__ dis2_b,
                       float* __restrict__ c4, float* __restrict__ w3,
                       float* __restrict__ biasc, float* __restrict__ W2p,
                       float* __restrict__ bias2c,
                       float* __restrict__ feat, float* __restrict__ g) {
  int i = blockIdx.x * blockDim.x + threadIdx.x;
  if (i < NPT) {
    float4 v;
    v.x = cloud[i*3+0]; v.y = cloud[i*3+1]; v.z = cloud[i*3+2]; v.w = 0.f;
    ((float4*)c4)[i] = v;
  }
  {
    int j = i - NPT;                       // 2*64*384 = 49152 elems
    if (j >= 0 && j < 2*64*384) {
      int h = j / 24576;
      int r = j - h*24576;
      int o = r / 384;
      int k = r - o*384;
      int t = k >> 7;
      int c = k & 127;
      const float* src = h ? dis1_w : seg1_w;
      w3[j] = src[o*384 + c*3 + t];        // w3[h][o][t*128+c] = w[o][c][t]
    }
  }
  {
    int j = i - (NPT + 49152);
    if (j >= 0 && j < 128) biasc[j] = (j < 64) ? seg1_b[j] : dis1_b[j-64];
  }
  {
    int j = i - (NPT + 49152 + 128);
    if (j >= 0 && j < 8192) {              // W2p[64][128] block-diagonal
      int o = j >> 7, c = j & 127;
      float v = 0.f;
      if (o < 32) { if (c < 64) v = seg2_w[o*64 + c]; }
      else        { if (c >= 64) v = dis2_w[(o-32)*64 + (c-64)]; }
      W2p[j] = v;
    }
  }
  {
    int j = i - (NPT + 49152 + 128 + 8192);
    if (j >= 0 && j < 64) bias2c[j] = (j < 32) ? seg2_b[j] : dis2_b[j-32];
  }
  {
    int j = i - (NPT + 49152 + 128 + 8192 + 64);
    if (j >= 0 && j < 128) g[j] = 0.f;
  }
  {
    int j = i - (NPT + 49152 + 128 + 8192 + 64 + 128);
    if (j >= 0 && j < NPT*32) {
      int n = j >> 5, ch = j & 31;
      feat[j] = img[ch*HWIMG + choose[n]];
    }
  }
}

// ---------------- KNN: 4 queries/block, threshold prune, no spill -------------
// T_ub = 32nd smallest of 256 per-thread mins (threads own disjoint candidate
// sets -> the 32 smallest mins witness 32 distinct candidates <= T_ub).
// Distances recomputed in filter pass (cheaper than spilling 64 floats/thread).
__global__ __launch_bounds__(256) void k_knn(const float4* __restrict__ c4,
                                             int* __restrict__ idxo, float* __restrict__ wo) {
  __shared__ float smin[4][256];
  __shared__ float sT[4];
  __shared__ float sd[4][KCAP];
  __shared__ int   sj[4][KCAP];
  __shared__ int   scnt[4];
  int tid = threadIdx.x, lane = tid & 63, wv = tid >> 6;
  int q0 = blockIdx.x * 4;
  float4 p0 = c4[q0], p1 = c4[q0+1], p2 = c4[q0+2], p3 = c4[q0+3];
  float m0 = INFINITY, m1 = INFINITY, m2 = INFINITY, m3 = INFINITY;
#define D2Q(P, CJ) ({ float dx_=(P).x-(CJ).x, dy_=(P).y-(CJ).y, dz_=(P).z-(CJ).z; dx_*dx_+dy_*dy_+dz_*dz_; })
  for (int t = 0; t < 32; ++t) {
    float4 cj = c4[t*256 + tid];
    m0 = fminf(m0, D2Q(p0, cj));
    m1 = fminf(m1, D2Q(p1, cj));
    m2 = fminf(m2, D2Q(p2, cj));
    m3 = fminf(m3, D2Q(p3, cj));
  }
  smin[0][tid] = m0; smin[1][tid] = m1; smin[2][tid] = m2; smin[3][tid] = m3;
  if (tid < 4) scnt[tid] = 0;
  __syncthreads();
  // wave wv extracts T_ub for query wv (value-only 32-bit keys; ties only
  // loosen T -> still a valid upper bound)
  {
    float4 vv = *(const float4*)&smin[wv][lane*4];
    float v0 = vv.x, v1 = vv.y, v2 = vv.z, v3 = vv.w;
#define CSV(a,b) { if (b < a) { float t_ = a; a = b; b = t_; } }
    CSV(v0,v2) CSV(v1,v3) CSV(v0,v1) CSV(v2,v3) CSV(v1,v2)
    float T = 0.f;
    for (int it = 0; it < 32; ++it) {
      float mn = v0;
#pragma unroll
      for (int o = 1; o < 64; o <<= 1) mn = fminf(mn, __shfl_xor(mn, o, 64));
      T = mn;
      if (v0 == mn) { v0 = v1; v1 = v2; v2 = v3; v3 = INFINITY; }
    }
    if (lane == 0) sT[wv] = T * 1.0000001f + 1e-30f;  // ulp guard for recompute
  }
  __syncthreads();
  float T0 = sT[0], T1 = sT[1], T2 = sT[2], T3 = sT[3];
  // filter pass: recompute distances, append survivors
  for (int t = 0; t < 32; ++t) {
    int j = t*256 + tid;
    float4 cj = c4[j];
    float d;
    d = D2Q(p0, cj); if (d <= T0) { int p = atomicAdd(&scnt[0],1); if (p < KCAP) { sd[0][p] = d; sj[0][p] = j; } }
    d = D2Q(p1, cj); if (d <= T1) { int p = atomicAdd(&scnt[1],1); if (p < KCAP) { sd[1][p] = d; sj[1][p] = j; } }
    d = D2Q(p2, cj); if (d <= T2) { int p = atomicAdd(&scnt[2],1); if (p < KCAP) { sd[2][p] = d; sj[2][p] = j; } }
    d = D2Q(p3, cj); if (d <= T3) { int p = atomicAdd(&scnt[3],1); if (p < KCAP) { sd[3][p] = d; sj[3][p] = j; } }
  }
  __syncthreads();
  // wave wv: exact top-32 of query wv's survivors via bitonic sort (+merge)
  int M = scnt[wv]; if (M > KCAP) M = KCAP;
  unsigned long long key = (lane < M)
      ? (((unsigned long long)__float_as_uint(sd[wv][lane]) << 32) | (unsigned)sj[wv][lane])
      : ~0ull;
  key = bsort64(key, lane);
  for (int base = 64; base < M; base += 64) {
    unsigned long long nk = (base + lane < M)
        ? (((unsigned long long)__float_as_uint(sd[wv][base+lane]) << 32) | (unsigned)sj[wv][base+lane])
        : ~0ull;
    nk = bsort64(nk, lane);
    nk = __shfl_xor(nk, 63, 64);           // reverse -> bitonic with key
    key = key < nk ? key : nk;             // 64 smallest of the 128 (bitonic)
    key = bmerge64(key, lane);
  }
  float dsel = __uint_as_float((unsigned)(key >> 32));
  int   jsel = (int)(unsigned)(key & 0xffffffffu);
  // softmax over lanes 0..31 (masks <32 keep halves separate)
  float v = -sqrtf(dsel);
  float mx = v;
#pragma unroll
  for (int o = 1; o < 32; o <<= 1) mx = fmaxf(mx, __shfl_xor(mx, o, 64));
  float e = expf(v - mx);
  float s = e;
#pragma unroll
  for (int o = 1; o < 32; o <<= 1) s += __shfl_xor(s, o, 64);
  if (lane < 32) {
    int q = q0 + wv;
    wo[q*32 + lane] = e / s;
    idxo[q*32 + lane] = jsel;
  }
}

// ---------------- tiled fp32 GEMM: C = act(A[M,K] @ W[N,K]^T + b) -------------
// TM=32 doubles the grid for the big-K GEMMs (256 blocks = 1 wave/SIMD was the
// occupancy hole); TM=64 keeps the FMA:LDS balance for wide-N launches.
template<int ACT, int TM>
__global__ __launch_bounds__(256) void k_gemm(const float* __restrict__ A,
                                              const float* __restrict__ W,
                                              const float* __restrict__ bias,
                                              float* __restrict__ C,
                                              int M, int N, int K) {
  constexpr int R = TM / 16;
  __shared__ float As[16][TM];
  __shared__ float Bs[16][64];
  int tid = threadIdx.x;
  int tx = tid & 15, ty = tid >> 4;
  int m0 = blockIdx.x * TM, n0 = blockIdx.y * 64;
  float acc[R][4] = {};
  for (int kc = 0; kc < K; kc += 16) {
#pragma unroll
    for (int i = 0; i < TM/16; ++i) {
      int lin = i*256 + tid;
      int mm = lin >> 4, kk = lin & 15;
      int kg = kc + kk;
      As[kk][mm] = (kg < K) ? A[(size_t)(m0+mm)*K + kg] : 0.f;
    }
#pragma unroll
    for (int i = 0; i < 4; ++i) {
      int lin = i*256 + tid;
      int mm = lin >> 4, kk = lin & 15;
      int kg = kc + kk;
      Bs[kk][mm] = (kg < K) ? W[(size_t)(n0+mm)*K + kg] : 0.f;
    }
    __syncthreads();
#pragma unroll
    for (int k = 0; k < 16; ++k) {
      float4 bv = *(const float4*)&Bs[k][tx*4];
      float a[R];
#pragma unroll
      for (int r = 0; r < R; ++r) a[r] = As[k][ty*R + r];
#pragma unroll
      for (int r = 0; r < R; ++r) {
        acc[r][0] += a[r]*bv.x; acc[r][1] += a[r]*bv.y;
        acc[r][2] += a[r]*bv.z; acc[r][3] += a[r]*bv.w;
      }
    }
    __syncthreads();
  }
#pragma unroll
  for (int r = 0; r < R; ++r) {
    int mm = m0 + ty*R + r;
#pragma unroll
    for (int j = 0; j < 4; ++j) {
      int nn = n0 + tx*4 + j;
      float v = acc[r][j] + bias[nn];
      if (ACT) v = lrelu(v);
      C[(size_t)mm*N + nn] = v;
    }
  }
  (void)M;
}

// ---------------- conv3 GEMM with fused im2col (K=384, N=128, TM=32) ----------
__global__ __launch_bounds__(256) void k_gemm_c3(const float* __restrict__ fused,
                                                 const float* __restrict__ W,
                                                 const float* __restrict__ bias,
                                                 float* __restrict__ C) {
  __shared__ float As[16][32];
  __shared__ float Bs[16][64];
  int tid = threadIdx.x, tx = tid & 15, ty = tid >> 4;
  int m0 = blockIdx.x * 32, n0 = blockIdx.y * 64;
  float acc[2][4] = {};
  for (int kc = 0; kc < 384; kc += 16) {
    int t = kc >> 7;           // 128 % 16 == 0 -> chunks never straddle taps
    int cb = kc & 127;
#pragma unroll
    for (int i = 0; i < 2; ++i) {
      int lin = i*256 + tid;
      int mm = lin >> 4, kk = lin & 15;
      int ns = m0 + mm + t - 1;
      As[kk][mm] = (ns >= 0 && ns < NPT) ? fused[(size_t)ns*128 + cb + kk] : 0.f;
    }
#pragma unroll
    for (int i = 0; i < 4; ++i) {
      int lin = i*256 + tid;
      int mm = lin >> 4, kk = lin & 15;
      Bs[kk][mm] = W[(size_t)(n0+mm)*384 + kc + kk];
    }
    __syncthreads();
#pragma unroll
    for (int k = 0; k < 16; ++k) {
      float4 bv = *(const float4*)&Bs[k][tx*4];
      float a0 = As[k][ty*2], a1 = As[k][ty*2+1];
      acc[0][0] += a0*bv.x; acc[0][1] += a0*bv.y; acc[0][2] += a0*bv.z; acc[0][3] += a0*bv.w;
      acc[1][0] += a1*bv.x; acc[1][1] += a1*bv.y; acc[1][2] += a1*bv.z; acc[1][3] += a1*bv.w;
    }
    __syncthreads();
  }
#pragma unroll
  for (int r = 0; r < 2; ++r) {
    int mm = m0 + ty*2 + r;
#pragma unroll
    for (int j = 0; j < 4; ++j) {
      int nn = n0 + tx*4 + j;
      C[(size_t)mm*128 + nn] = lrelu(acc[r][j] + bias[nn]);
    }
  }
}

// ---------------- head GEMM (t1sd @ W2p^T, N=64, K=128) + fused 1-d heads -----
__global__ __launch_bounds__(256) void k_gemm_head(const float* __restrict__ A,
                                                   const float* __restrict__ W,
                                                   const float* __restrict__ bias,
                                                   const float* __restrict__ segw, const float* __restrict__ segb,
                                                   const float* __restrict__ disw, const float* __restrict__ disb,
                                                   float* __restrict__ osegp, float* __restrict__ odisp) {
  __shared__ float As[16][32];
  __shared__ float Bs[16][64];
  __shared__ float sred[32][17];
  int tid = threadIdx.x, tx = tid & 15, ty = tid >> 4;
  int m0 = blockIdx.x * 32;
  float acc[2][4] = {};
  for (int kc = 0; kc < 128; kc += 16) {
#pragma unroll
    for (int i = 0; i < 2; ++i) {
      int lin = i*256 + tid;
      int mm = lin >> 4, kk = lin & 15;
      As[kk][mm] = A[(size_t)(m0+mm)*128 + kc + kk];
    }
#pragma unroll
    for (int i = 0; i < 4; ++i) {
      int lin = i*256 + tid;
      int mm = lin >> 4, kk = lin & 15;
      Bs[kk][mm] = W[(size_t)mm*128 + kc + kk];
    }
    __syncthreads();
#pragma unroll
    for (int k = 0; k < 16; ++k) {
      float4 bv = *(const float4*)&Bs[k][tx*4];
      float a0 = As[k][ty*2], a1 = As[k][ty*2+1];
      acc[0][0] += a0*bv.x; acc[0][1] += a0*bv.y; acc[0][2] += a0*bv.z; acc[0][3] += a0*bv.w;
      acc[1][0] += a1*bv.x; acc[1][1] += a1*bv.y; acc[1][2] += a1*bv.z; acc[1][3] += a1*bv.w;
    }
    __syncthreads();
  }
  float hw[4];
#pragma unroll
  for (int j = 0; j < 4; ++j) {
    int c = tx*4 + j;
    hw[j] = (c < 32) ? segw[c] : disw[c - 32];
  }
#pragma unroll
  for (int r = 0; r < 2; ++r) {
    float s = 0.f;
#pragma unroll
    for (int j = 0; j < 4; ++j) {
      int c = tx*4 + j;
      s += lrelu(acc[r][j] + bias[c]) * hw[j];
    }
    sred[ty*2 + r][tx] = s;
  }
  __syncthreads();
  if (tid < 32) {
    float a = 0.f, b = 0.f;
#pragma unroll
    for (int t2 = 0; t2 < 8; ++t2)  a += sred[tid][t2];
#pragma unroll
    for (int t2 = 8; t2 < 16; ++t2) b += sred[tid][t2];
    osegp[m0 + tid] = a + segb[0];
    odisp[m0 + tid] = b + disb[0];
  }
}

// ---------------- pool: weighted max over 32 neighbors + build final[416] -----
__global__ __launch_bounds__(256) void k_pool(const float* __restrict__ Yf,
                                              const float* __restrict__ Yfp,
                                              const float* __restrict__ feat,
                                              const float* __restrict__ pf,
                                              const int* __restrict__ idx,
                                              const float* __restrict__ w,
                                              float* __restrict__ fin) {
  int n = blockIdx.x;
  int tid = threadIdx.x;
  __shared__ int sj[32];
  __shared__ float sw[32];
  if (tid < 32) { sj[tid] = idx[n*32+tid]; sw[tid] = w[n*32+tid]; }
  __syncthreads();
  if (tid < 128) {
    int c = tid;
    float acc = -INFINITY;
#pragma unroll 8
    for (int k = 0; k < 32; ++k) acc = fmaxf(acc, sw[k] * Yfp[(size_t)sj[k]*128 + c]);
    fin[(size_t)n*416 + c] = lrelu(acc);                 // fp  [0,128)
    fin[(size_t)n*416 + 288 + c] = lrelu(pf[n*128 + c]); // pf  [288,416)
    if (c < 32) fin[(size_t)n*416 + 128 + c] = lrelu(feat[n*32 + c]); // feat [128,160)
  } else {
    int c = tid - 128;
    float acc = -INFINITY;
#pragma unroll 8
    for (int k = 0; k < 32; ++k) acc = fmaxf(acc, sw[k] * Yf[(size_t)sj[k]*128 + c]);
    fin[(size_t)n*416 + 160 + c] = lrelu(acc);           // f   [160,288)
  }
}

// ---------------- dis_center softmax ------------------------------------------
__global__ __launch_bounds__(1024) void k_discenter(const float* __restrict__ cloud,
                                                    const float* __restrict__ tvec,
                                                    float* __restrict__ dc) {
  __shared__ float sred[16];
  __shared__ float sbc[2];
  int tid = threadIdx.x;
  float tx = tvec[0], ty = tvec[1], tz = tvec[2];
  float v[8];
#pragma unroll
  for (int i = 0; i < 8; ++i) {
    int n = i*1024 + tid;
    float ax = cloud[n*3+0] + tx, ay = cloud[n*3+1] + ty, az = cloud[n*3+2] + tz;
    v[i] = sqrtf(ax*ax + ay*ay + az*az);
  }
  float m = v[0];
#pragma unroll
  for (int i = 1; i < 8; ++i) m = fmaxf(m, v[i]);
#pragma unroll
  for (int o = 1; o < 64; o <<= 1) m = fmaxf(m, __shfl_xor(m, o, 64));
  if ((tid & 63) == 0) sred[tid >> 6] = m;
  __syncthreads();
  if (tid == 0) {
    float mm = sred[0];
    for (int i = 1; i < 16; ++i) mm = fmaxf(mm, sred[i]);
    sbc[0] = mm;
  }
  __syncthreads();
  float gm = sbc[0];
  float e[8]; float s = 0.f;
#pragma unroll
  for (int i = 0; i < 8; ++i) { e[i] = expf(v[i] - gm); s += e[i]; }
#pragma unroll
  for (int o = 1; o < 64; o <<= 1) s += __shfl_xor(s, o, 64);
  __syncthreads();
  if ((tid & 63) == 0) sred[tid >> 6] = s;
  __syncthreads();
  if (tid == 0) {
    float ss = 0.f;
    for (int i = 0; i < 16; ++i) ss += sred[i];
    sbc[1] = ss;
  }
  __syncthreads();
  float gs = sbc[1];
#pragma unroll
  for (int i = 0; i < 8; ++i) dc[i*1024 + tid] = e[i] / gs;
}

// ---------------- g = sum_n fused[n]*dc[n]*seg[n] ------------------------------
__global__ __launch_bounds__(256) void k_g(const float* __restrict__ fused,
                                           const float* __restrict__ dc,
                                           const float* __restrict__ seg,
                                           float* __restrict__ g) {
  __shared__ float sbuf[256];
  int tid = threadIdx.x;
  int c = tid & 127, h = tid >> 7;
  float acc = 0.f;
  for (int r = 0; r < 128; ++r) {
    int n = blockIdx.x*256 + r*2 + h;
    acc += fused[(size_t)n*128 + c] * dc[n] * seg[n];
  }
  sbuf[tid] = acc;
  __syncthreads();
  if (tid < 128) atomicAdd(&g[c], sbuf[tid] + sbuf[tid+128]);
}

// ---------------- keypoint MLP 128->90->64->24 ---------------------------------
__global__ __launch_bounds__(128) void k_kp(const float* __restrict__ g,
                                            const float* __restrict__ l1w, const float* __restrict__ l1b,
                                            const float* __restrict__ l2w, const float* __restrict__ l2b,
                                            const float* __restrict__ l3w, const float* __restrict__ l3b,
                                            float* __restrict__ outp) {
  __shared__ float sg[128], s1[90], s2[64];
  int tid = threadIdx.x;
  sg[tid] = g[tid];
  __syncthreads();
  if (tid < 90) {
    float a = l1b[tid];
    for (int i = 0; i < 128; ++i) a += sg[i]*l1w[tid*128+i];
    s1[tid] = lrelu(a);
  }
  __syncthreads();
  if (tid < 64) {
    float a = l2b[tid];
    for (int i = 0; i < 90; ++i) a += s1[i]*l2w[tid*90+i];
    s2[tid] = lrelu(a);
  }
  __syncthreads();
  if (tid < 24) {
    float a = l3b[tid];
    for (int i = 0; i < 64; ++i) a += s2[i]*l3w[tid*64+i];
    outp[tid] = a;
  }
}

extern "C" void kernel_launch(void* const* d_in, const int* in_sizes, int n_in,
                              void* d_out, int out_size, void* d_ws, size_t ws_size,
                              hipStream_t stream) {
  const float* seg      = (const float*)d_in[0];
  const float* img      = (const float*)d_in[1];
  const float* cloud    = (const float*)d_in[2];
  const float* tvec     = (const float*)d_in[3];
  const int*   choose   = (const int*)d_in[4];
  const float* pconv1_w = (const float*)d_in[5];
  const float* pconv1_b = (const float*)d_in[6];
  const float* pconv2_w = (const float*)d_in[7];
  const float* pconv2_b = (const float*)d_in[8];
  const float* conv1_w  = (const float*)d_in[9];
  const float* conv1_b  = (const float*)d_in[10];
  const float* conv2_w  = (const float*)d_in[11];
  const float* conv2_b  = (const float*)d_in[12];
  const float* psconv1_w= (const float*)d_in[13];
  const float* psconv1_b= (const float*)d_in[14];
  const float* psconv2_w= (const float*)d_in[15];
  const float* psconv2_b= (const float*)d_in[16];
  const float* final_w  = (const float*)d_in[17];
  const float* final_b  = (const float*)d_in[18];
  const float* seg1_w   = (const float*)d_in[19];
  const float* seg1_b   = (const float*)d_in[20];
  const float* seg2_w   = (const float*)d_in[21];
  const float* seg2_b   = (const float*)d_in[22];
  const float* seg3_w   = (const float*)d_in[23];
  const float* seg3_b   = (const float*)d_in[24];
  const float* dis1_w   = (const float*)d_in[25];
  const float* dis1_b   = (const float*)d_in[26];
  const float* dis2_w   = (const float*)d_in[27];
  const float* dis2_b   = (const float*)d_in[28];
  const float* dis3_w   = (const float*)d_in[29];
  const float* dis3_b   = (const float*)d_in[30];
  const float* lin1_w   = (const float*)d_in[31];
  const float* lin1_b   = (const float*)d_in[32];
  const float* lin2_w   = (const float*)d_in[33];
  const float* lin2_b   = (const float*)d_in[34];
  const float* lin3_w   = (const float*)d_in[35];
  const float* lin3_b   = (const float*)d_in[36];

  float* out = (float*)d_out;
  float* ws  = (float*)d_ws;

  // workspace layout (floats)
  float* c4    = ws + 0;         // 32768
  float* feat  = ws + 32768;     // 262144
  float* h1    = ws + 294912;    // 524288  (yh alias)
  float* pf    = ws + 819200;    // 1048576
  float* Yf    = ws + 1867776;   // 1048576
  float* ph    = ws + 2916352;   // 2097152 (t1sd alias)
  float* Yfp   = ws + 5013504;   // 1048576
  int*   idx   = (int*)(ws + 6062080);  // 262144
  float* wsm   = ws + 6324224;   // 262144
  float* fin   = ws + 6586368;   // 3407872
  float* fused = ws + 9994240;   // 1048576
  float* w3    = ws + 11042816;  // 49152 (seg then dis)
  float* biasc = ws + 11091968;  // 128
  float* W2p   = ws + 11092096;  // 8192
  float* bias2c= ws + 11100288;  // 64
  float* g     = ws + 11100352;  // 128
  float* yh    = h1;
  float* t1sd  = ph;

  float* o_kp   = out;            // 24
  float* o_disp = out + 24;       // 8192
  float* o_dc   = out + 8216;     // 8192
  float* o_segp = out + 16408;    // 8192

  k_prep<<<1282, 256, 0, stream>>>(cloud, choose, img, seg1_w, dis1_w,
                                   seg1_b, dis1_b, seg2_w, dis2_w, seg2_b, dis2_b,
                                   c4, w3, biasc, W2p, bias2c, feat, g);

  // point MLP: cloud -> h1 -> pf
  k_gemm<1,32><<<dim3(256,1), 256, 0, stream>>>(cloud, pconv1_w, pconv1_b, h1, NPT, 64, 3);
  k_gemm<0,32><<<dim3(256,2), 256, 0, stream>>>(h1, pconv2_w, pconv2_b, pf, NPT, 128, 64);

  k_knn<<<2048, 256, 0, stream>>>((const float4*)c4, idx, wsm);

  // per-point MLPs (gather-commuted)
  k_gemm<1,32><<<dim3(256,1), 256, 0, stream>>>(feat, conv1_w, conv1_b, yh, NPT, 64, 32);
  k_gemm<0,32><<<dim3(256,2), 256, 0, stream>>>(yh, conv2_w, conv2_b, Yf, NPT, 128, 64);
  k_gemm<1,64><<<dim3(128,4), 256, 0, stream>>>(pf, psconv1_w, psconv1_b, ph, NPT, 256, 128);
  k_gemm<0,32><<<dim3(256,2), 256, 0, stream>>>(ph, psconv2_w, psconv2_b, Yfp, NPT, 128, 256);

  k_pool<<<NPT, 256, 0, stream>>>(Yf, Yfp, feat, pf, idx, wsm, fin);

  k_gemm<0,32><<<dim3(256,2), 256, 0, stream>>>(fin, final_w, final_b, fused, NPT, 128, 416);

  // merged seg|dis head chains (im2col fused into the conv3 GEMM)
  k_gemm_c3<<<dim3(256,2), 256, 0, stream>>>(fused, w3, biasc, t1sd);
  k_gemm_head<<<256, 256, 0, stream>>>(t1sd, W2p, bias2c, seg3_w, seg3_b, dis3_w, dis3_b,
                                       o_segp, o_disp);

  k_discenter<<<1, 1024, 0, stream>>>(cloud, tvec, o_dc);

  k_g<<<32, 256, 0, stream>>>(fused, o_dc, seg, g);
  k_kp<<<1, 128, 0, stream>>>(g, lin1_w, lin1_b, lin2_w, lin2_b, lin3_w, lin3_b, o_kp);

  (void)in_sizes; (void)n_in; (void)out_size; (void)ws_size;
}

// Round 4
// 366.885 us; speedup vs baseline: 1.7451x; 1.0437x over previous
//
#include <hip/hip_runtime.h>
#include <math.h>

#define NPT 8192
#define HWIMG 19200
#define KCAP 128

using short8 = __attribute__((ext_vector_type(8))) short;
using f32x4  = __attribute__((ext_vector_type(4))) float;

__device__ __forceinline__ float lrelu(float x) { return x > 0.f ? x : 0.01f * x; }
__device__ __forceinline__ unsigned short f2bf(float v) {
  unsigned u = __float_as_uint(v);
  return (unsigned short)((u + 0x7fffu + ((u >> 16) & 1u)) >> 16);
}
__device__ __forceinline__ float bf2f(unsigned short h) {
  return __uint_as_float(((unsigned)h) << 16);
}

// weight-plane segment offsets (in shorts)
#define OFF_PCONV2  0
#define OFF_CONV1   8192
#define OFF_CONV2   10240
#define OFF_PSCONV1 18432
#define OFF_PSCONV2 51200
#define OFF_FINAL   83968
#define OFF_W3      137216
#define OFF_W2P     186368
#define NSPLIT      194560

// ---------------- prep: c4 pack, w3 transpose, head tables, feat gather+split -
__global__ void k_prep(const float* __restrict__ cloud, const int* __restrict__ choose,
                       const float* __restrict__ img,
                       const float* __restrict__ seg1_w, const float* __restrict__ dis1_w,
                       const float* __restrict__ seg1_b, const float* __restrict__ dis1_b,
                       const float* __restrict__ seg2_w, const float* __restrict__ dis2_w,
                       const float* __restrict__ seg2_b, const float* __restrict__ dis2_b,
                       float* __restrict__ c4, float* __restrict__ w3,
                       float* __restrict__ biasc, float* __restrict__ W2p,
                       float* __restrict__ bias2c,
                       float* __restrict__ feat, unsigned short* __restrict__ feat_h,
                       unsigned short* __restrict__ feat_l, float* __restrict__ g) {
  int i = blockIdx.x * blockDim.x + threadIdx.x;
  if (i < NPT) {
    float4 v;
    v.x = cloud[i*3+0]; v.y = cloud[i*3+1]; v.z = cloud[i*3+2]; v.w = 0.f;
    ((float4*)c4)[i] = v;
  }
  {
    int j = i - NPT;                       // 2*64*384 = 49152 elems
    if (j >= 0 && j < 2*64*384) {
      int h = j / 24576;
      int r = j - h*24576;
      int o = r / 384;
      int k = r - o*384;
      int t = k >> 7;
      int c = k & 127;
      const float* src = h ? dis1_w : seg1_w;
      w3[j] = src[o*384 + c*3 + t];        // w3[h][o][t*128+c] = w[o][c][t]
    }
  }
  {
    int j = i - (NPT + 49152);
    if (j >= 0 && j < 128) biasc[j] = (j < 64) ? seg1_b[j] : dis1_b[j-64];
  }
  {
    int j = i - (NPT + 49152 + 128);
    if (j >= 0 && j < 8192) {              // W2p[64][128] block-diagonal
      int o = j >> 7, c = j & 127;
      float v = 0.f;
      if (o < 32) { if (c < 64) v = seg2_w[o*64 + c]; }
      else        { if (c >= 64) v = dis2_w[(o-32)*64 + (c-64)]; }
      W2p[j] = v;
    }
  }
  {
    int j = i - (NPT + 49152 + 128 + 8192);
    if (j >= 0 && j < 64) bias2c[j] = (j < 32) ? seg2_b[j] : dis2_b[j-32];
  }
  {
    int j = i - (NPT + 49152 + 128 + 8192 + 64);
    if (j >= 0 && j < 128) g[j] = 0.f;
  }
  {
    int j = i - (NPT + 49152 + 128 + 8192 + 64 + 128);
    if (j >= 0 && j < NPT*32) {
      int n = j >> 5, ch = j & 31;
      float v = img[ch*HWIMG + choose[n]];
      feat[j] = v;
      unsigned short h = f2bf(v);
      feat_h[j] = h;
      feat_l[j] = f2bf(v - bf2f(h));
    }
  }
}

// ---------------- weight splitter: fp32 -> (hi, lo) bf16 planes ---------------
__global__ void k_split(const float* __restrict__ pconv2_w, const float* __restrict__ conv1_w,
                        const float* __restrict__ conv2_w, const float* __restrict__ psconv1_w,
                        const float* __restrict__ psconv2_w, const float* __restrict__ final_w,
                        const float* __restrict__ w3f, const float* __restrict__ W2pf,
                        unsigned short* __restrict__ Wh, unsigned short* __restrict__ Wl) {
  int i = blockIdx.x * blockDim.x + threadIdx.x;
  if (i >= NSPLIT) return;
  float v;
  if      (i < OFF_CONV1)   v = pconv2_w[i];
  else if (i < OFF_CONV2)   v = conv1_w[i - OFF_CONV1];
  else if (i < OFF_PSCONV1) v = conv2_w[i - OFF_CONV2];
  else if (i < OFF_PSCONV2) v = psconv1_w[i - OFF_PSCONV1];
  else if (i < OFF_FINAL)   v = psconv2_w[i - OFF_PSCONV2];
  else if (i < OFF_W3)      v = final_w[i - OFF_FINAL];
  else if (i < OFF_W2P)     v = w3f[i - OFF_W3];
  else                      v = W2pf[i - OFF_W2P];
  unsigned short h = f2bf(v);
  Wh[i] = h;
  Wl[i] = f2bf(v - bf2f(h));
}

// ---------------- KNN: 4 queries/block, threshold prune (unchanged) -----------
__device__ __forceinline__ unsigned long long bsort64(unsigned long long key, int lane) {
#pragma unroll
  for (int k = 2; k <= 64; k <<= 1) {
#pragma unroll
    for (int j = k >> 1; j > 0; j >>= 1) {
      unsigned long long o = __shfl_xor(key, j, 64);
      bool keepmin = (((lane & j) == 0) == ((lane & k) == 0));
      bool omin = o < key;
      key = (omin == keepmin) ? o : key;
    }
  }
  return key;
}
__device__ __forceinline__ unsigned long long bmerge64(unsigned long long key, int lane) {
#pragma unroll
  for (int j = 32; j > 0; j >>= 1) {
    unsigned long long o = __shfl_xor(key, j, 64);
    bool keepmin = ((lane & j) == 0);
    bool omin = o < key;
    key = (omin == keepmin) ? o : key;
  }
  return key;
}

__global__ __launch_bounds__(256) void k_knn(const float4* __restrict__ c4,
                                             int* __restrict__ idxo, float* __restrict__ wo) {
  __shared__ float smin[4][256];
  __shared__ float sT[4];
  __shared__ float sd[4][KCAP];
  __shared__ int   sj[4][KCAP];
  __shared__ int   scnt[4];
  int tid = threadIdx.x, lane = tid & 63, wv = tid >> 6;
  int q0 = blockIdx.x * 4;
  float4 p0 = c4[q0], p1 = c4[q0+1], p2 = c4[q0+2], p3 = c4[q0+3];
  float m0 = INFINITY, m1 = INFINITY, m2 = INFINITY, m3 = INFINITY;
#define D2Q(P, CJ) ({ float dx_=(P).x-(CJ).x, dy_=(P).y-(CJ).y, dz_=(P).z-(CJ).z; dx_*dx_+dy_*dy_+dz_*dz_; })
  for (int t = 0; t < 32; ++t) {
    float4 cj = c4[t*256 + tid];
    m0 = fminf(m0, D2Q(p0, cj));
    m1 = fminf(m1, D2Q(p1, cj));
    m2 = fminf(m2, D2Q(p2, cj));
    m3 = fminf(m3, D2Q(p3, cj));
  }
  smin[0][tid] = m0; smin[1][tid] = m1; smin[2][tid] = m2; smin[3][tid] = m3;
  if (tid < 4) scnt[tid] = 0;
  __syncthreads();
  {
    float4 vv = *(const float4*)&smin[wv][lane*4];
    float v0 = vv.x, v1 = vv.y, v2 = vv.z, v3 = vv.w;
#define CSV(a,b) { if (b < a) { float t_ = a; a = b; b = t_; } }
    CSV(v0,v2) CSV(v1,v3) CSV(v0,v1) CSV(v2,v3) CSV(v1,v2)
    float T = 0.f;
    for (int it = 0; it < 32; ++it) {
      float mn = v0;
#pragma unroll
      for (int o = 1; o < 64; o <<= 1) mn = fminf(mn, __shfl_xor(mn, o, 64));
      T = mn;
      if (v0 == mn) { v0 = v1; v1 = v2; v2 = v3; v3 = INFINITY; }
    }
    if (lane == 0) sT[wv] = T * 1.0000001f + 1e-30f;
  }
  __syncthreads();
  float T0 = sT[0], T1 = sT[1], T2 = sT[2], T3 = sT[3];
  for (int t = 0; t < 32; ++t) {
    int j = t*256 + tid;
    float4 cj = c4[j];
    float d;
    d = D2Q(p0, cj); if (d <= T0) { int p = atomicAdd(&scnt[0],1); if (p < KCAP) { sd[0][p] = d; sj[0][p] = j; } }
    d = D2Q(p1, cj); if (d <= T1) { int p = atomicAdd(&scnt[1],1); if (p < KCAP) { sd[1][p] = d; sj[1][p] = j; } }
    d = D2Q(p2, cj); if (d <= T2) { int p = atomicAdd(&scnt[2],1); if (p < KCAP) { sd[2][p] = d; sj[2][p] = j; } }
    d = D2Q(p3, cj); if (d <= T3) { int p = atomicAdd(&scnt[3],1); if (p < KCAP) { sd[3][p] = d; sj[3][p] = j; } }
  }
  __syncthreads();
  int M = scnt[wv]; if (M > KCAP) M = KCAP;
  unsigned long long key = (lane < M)
      ? (((unsigned long long)__float_as_uint(sd[wv][lane]) << 32) | (unsigned)sj[wv][lane])
      : ~0ull;
  key = bsort64(key, lane);
  for (int base = 64; base < M; base += 64) {
    unsigned long long nk = (base + lane < M)
        ? (((unsigned long long)__float_as_uint(sd[wv][base+lane]) << 32) | (unsigned)sj[wv][base+lane])
        : ~0ull;
    nk = bsort64(nk, lane);
    nk = __shfl_xor(nk, 63, 64);
    key = key < nk ? key : nk;
    key = bmerge64(key, lane);
  }
  float dsel = __uint_as_float((unsigned)(key >> 32));
  int   jsel = (int)(unsigned)(key & 0xffffffffu);
  float v = -sqrtf(dsel);
  float mx = v;
#pragma unroll
  for (int o = 1; o < 32; o <<= 1) mx = fmaxf(mx, __shfl_xor(mx, o, 64));
  float e = expf(v - mx);
  float s = e;
#pragma unroll
  for (int o = 1; o < 32; o <<= 1) s += __shfl_xor(s, o, 64);
  if (lane < 32) {
    int q = q0 + wv;
    wo[q*32 + lane] = e / s;
    idxo[q*32 + lane] = jsel;
  }
}

// ---------------- fp32 GEMM (only pconv1, K=3), split-bf16 output -------------
template<int ACT>
__global__ __launch_bounds__(256) void k_gemm_s(const float* __restrict__ A,
                                                const float* __restrict__ W,
                                                const float* __restrict__ bias,
                                                unsigned short* __restrict__ Ch,
                                                unsigned short* __restrict__ Cl,
                                                int M, int N, int K) {
  __shared__ float As[16][32];
  __shared__ float Bs[16][64];
  int tid = threadIdx.x, tx = tid & 15, ty = tid >> 4;
  int m0 = blockIdx.x * 32, n0 = blockIdx.y * 64;
  float acc[2][4] = {};
  for (int kc = 0; kc < K; kc += 16) {
#pragma unroll
    for (int i = 0; i < 2; ++i) {
      int lin = i*256 + tid;
      int mm = lin >> 4, kk = lin & 15;
      int kg = kc + kk;
      As[kk][mm] = (kg < K) ? A[(size_t)(m0+mm)*K + kg] : 0.f;
    }
#pragma unroll
    for (int i = 0; i < 4; ++i) {
      int lin = i*256 + tid;
      int mm = lin >> 4, kk = lin & 15;
      int kg = kc + kk;
      Bs[kk][mm] = (kg < K && (n0+mm) < N) ? W[(size_t)(n0+mm)*K + kg] : 0.f;
    }
    __syncthreads();
#pragma unroll
    for (int k = 0; k < 16; ++k) {
      float4 bv = *(const float4*)&Bs[k][tx*4];
      float a0 = As[k][ty*2], a1 = As[k][ty*2+1];
      acc[0][0] += a0*bv.x; acc[0][1] += a0*bv.y; acc[0][2] += a0*bv.z; acc[0][3] += a0*bv.w;
      acc[1][0] += a1*bv.x; acc[1][1] += a1*bv.y; acc[1][2] += a1*bv.z; acc[1][3] += a1*bv.w;
    }
    __syncthreads();
  }
#pragma unroll
  for (int r = 0; r < 2; ++r) {
    int mm = m0 + ty*2 + r;
#pragma unroll
    for (int j = 0; j < 4; ++j) {
      int nn = n0 + tx*4 + j;
      if (nn < N) {
        float v = acc[r][j] + bias[nn];
        if (ACT) v = lrelu(v);
        unsigned short h = f2bf(v);
        Ch[(size_t)mm*N + nn] = h;
        Cl[(size_t)mm*N + nn] = f2bf(v - bf2f(h));
      }
    }
  }
  (void)M;
}

// ---------------- split-bf16 MFMA GEMM: C = act(A @ W^T + b) ------------------
// A,W stored as hi/lo bf16 planes, row-major [M,K]/[N,K]. One wave per 16 rows.
// D = Ah*Wh + Al*Wh + Ah*Wl (fp32 acc) -> ~1e-5 rel accuracy.
// OM: 0 = fp32 out, 1 = split out, 2 = both
template<int K, int NT, int ACT, int OM>
__global__ __launch_bounds__(64) void k_mg(const unsigned short* __restrict__ Ah,
                                           const unsigned short* __restrict__ Al,
                                           const unsigned short* __restrict__ Wh,
                                           const unsigned short* __restrict__ Wl,
                                           const float* __restrict__ bias,
                                           float* __restrict__ Cf,
                                           unsigned short* __restrict__ Ch,
                                           unsigned short* __restrict__ Cl) {
  constexpr int N = NT * 16;
  int lane = threadIdx.x;
  int mr = lane & 15, quad = lane >> 4;
  int m0 = blockIdx.x * 16;
  f32x4 acc[NT];
#pragma unroll
  for (int t = 0; t < NT; ++t) { f32x4 z = {0.f,0.f,0.f,0.f}; acc[t] = z; }
  const unsigned short* arh = Ah + (size_t)(m0 + mr) * K + quad * 8;
  const unsigned short* arl = Al + (size_t)(m0 + mr) * K + quad * 8;
  const unsigned short* wrh = Wh + (size_t)mr * K + quad * 8;
  const unsigned short* wrl = Wl + (size_t)mr * K + quad * 8;
#pragma unroll
  for (int ks = 0; ks < K / 32; ++ks) {
    short8 ah = *(const short8*)(arh + ks * 32);
    short8 al = *(const short8*)(arl + ks * 32);
#pragma unroll
    for (int t = 0; t < NT; ++t) {
      short8 wh = *(const short8*)(wrh + (size_t)t * 16 * K + ks * 32);
      short8 wl = *(const short8*)(wrl + (size_t)t * 16 * K + ks * 32);
      acc[t] = __builtin_amdgcn_mfma_f32_16x16x32_bf16(ah, wh, acc[t], 0, 0, 0);
      acc[t] = __builtin_amdgcn_mfma_f32_16x16x32_bf16(al, wh, acc[t], 0, 0, 0);
      acc[t] = __builtin_amdgcn_mfma_f32_16x16x32_bf16(ah, wl, acc[t], 0, 0, 0);
    }
  }
#pragma unroll
  for (int t = 0; t < NT; ++t) {
    int n = t * 16 + mr;
    float b = bias[n];
#pragma unroll
    for (int r = 0; r < 4; ++r) {
      int row = m0 + quad * 4 + r;
      float v = acc[t][r] + b;
      if (ACT) v = lrelu(v);
      if (OM != 1) Cf[(size_t)row * N + n] = v;
      if (OM >= 1) {
        unsigned short h = f2bf(v);
        Ch[(size_t)row * N + n] = h;
        Cl[(size_t)row * N + n] = f2bf(v - bf2f(h));
      }
    }
  }
}

// ---------------- conv3 MFMA GEMM with fused im2col (K=384, N=128) ------------
__global__ __launch_bounds__(64) void k_mg_c3(const unsigned short* __restrict__ Ah,
                                              const unsigned short* __restrict__ Al,
                                              const unsigned short* __restrict__ Wh,
                                              const unsigned short* __restrict__ Wl,
                                              const float* __restrict__ bias,
                                              unsigned short* __restrict__ Ch,
                                              unsigned short* __restrict__ Cl) {
  int lane = threadIdx.x;
  int mr = lane & 15, quad = lane >> 4;
  int m0 = blockIdx.x * 16;
  f32x4 acc[8];
#pragma unroll
  for (int t = 0; t < 8; ++t) { f32x4 z = {0.f,0.f,0.f,0.f}; acc[t] = z; }
  const unsigned short* wrh = Wh + (size_t)mr * 384 + quad * 8;
  const unsigned short* wrl = Wl + (size_t)mr * 384 + quad * 8;
#pragma unroll
  for (int ks = 0; ks < 12; ++ks) {
    int tap = ks >> 2;
    int kin = (ks & 3) * 32 + quad * 8;
    int ar = m0 + mr + tap - 1;
    short8 ah = {0,0,0,0,0,0,0,0}, al = {0,0,0,0,0,0,0,0};
    if (ar >= 0 && ar < NPT) {
      ah = *(const short8*)(Ah + (size_t)ar * 128 + kin);
      al = *(const short8*)(Al + (size_t)ar * 128 + kin);
    }
#pragma unroll
    for (int t = 0; t < 8; ++t) {
      short8 wh = *(const short8*)(wrh + (size_t)t * 16 * 384 + ks * 32);
      short8 wl = *(const short8*)(wrl + (size_t)t * 16 * 384 + ks * 32);
      acc[t] = __builtin_amdgcn_mfma_f32_16x16x32_bf16(ah, wh, acc[t], 0, 0, 0);
      acc[t] = __builtin_amdgcn_mfma_f32_16x16x32_bf16(al, wh, acc[t], 0, 0, 0);
      acc[t] = __builtin_amdgcn_mfma_f32_16x16x32_bf16(ah, wl, acc[t], 0, 0, 0);
    }
  }
#pragma unroll
  for (int t = 0; t < 8; ++t) {
    int n = t * 16 + mr;
    float b = bias[n];
#pragma unroll
    for (int r = 0; r < 4; ++r) {
      int row = m0 + quad * 4 + r;
      float v = lrelu(acc[t][r] + b);
      unsigned short h = f2bf(v);
      Ch[(size_t)row * 128 + n] = h;
      Cl[(size_t)row * 128 + n] = f2bf(v - bf2f(h));
    }
  }
}

// ---------------- head MFMA GEMM (K=128, N=64) + fused 1-wide heads -----------
__global__ __launch_bounds__(64) void k_mg_head(const unsigned short* __restrict__ Ah,
                                                const unsigned short* __restrict__ Al,
                                                const unsigned short* __restrict__ Wh,
                                                const unsigned short* __restrict__ Wl,
                                                const float* __restrict__ bias,
                                                const float* __restrict__ segw, const float* __restrict__ segb,
                                                const float* __restrict__ disw, const float* __restrict__ disb,
                                                float* __restrict__ osegp, float* __restrict__ odisp) {
  __shared__ float sseg[16][16];
  __shared__ float sdis[16][16];
  int lane = threadIdx.x;
  int mr = lane & 15, quad = lane >> 4;
  int m0 = blockIdx.x * 16;
  f32x4 acc[4];
#pragma unroll
  for (int t = 0; t < 4; ++t) { f32x4 z = {0.f,0.f,0.f,0.f}; acc[t] = z; }
  const unsigned short* arh = Ah + (size_t)(m0 + mr) * 128 + quad * 8;
  const unsigned short* arl = Al + (size_t)(m0 + mr) * 128 + quad * 8;
  const unsigned short* wrh = Wh + (size_t)mr * 128 + quad * 8;
  const unsigned short* wrl = Wl + (size_t)mr * 128 + quad * 8;
#pragma unroll
  for (int ks = 0; ks < 4; ++ks) {
    short8 ah = *(const short8*)(arh + ks * 32);
    short8 al = *(const short8*)(arl + ks * 32);
#pragma unroll
    for (int t = 0; t < 4; ++t) {
      short8 wh = *(const short8*)(wrh + (size_t)t * 16 * 128 + ks * 32);
      short8 wl = *(const short8*)(wrl + (size_t)t * 16 * 128 + ks * 32);
      acc[t] = __builtin_amdgcn_mfma_f32_16x16x32_bf16(ah, wh, acc[t], 0, 0, 0);
      acc[t] = __builtin_amdgcn_mfma_f32_16x16x32_bf16(al, wh, acc[t], 0, 0, 0);
      acc[t] = __builtin_amdgcn_mfma_f32_16x16x32_bf16(ah, wl, acc[t], 0, 0, 0);
    }
  }
  float hwseg[2], hwdis[2];
  hwseg[0] = segw[mr]; hwseg[1] = segw[16 + mr];
  hwdis[0] = disw[mr]; hwdis[1] = disw[16 + mr];
#pragma unroll
  for (int r = 0; r < 4; ++r) {
    float ss = 0.f, ds = 0.f;
#pragma unroll
    for (int t = 0; t < 4; ++t) {
      float v = lrelu(acc[t][r] + bias[t * 16 + mr]);
      if (t < 2) ss += v * hwseg[t];
      else       ds += v * hwdis[t - 2];
    }
    sseg[quad * 4 + r][mr] = ss;
    sdis[quad * 4 + r][mr] = ds;
  }
  __syncthreads();
  if (lane < 16) {
    float a = 0.f;
#pragma unroll
    for (int i = 0; i < 16; ++i) a += sseg[lane][i];
    osegp[m0 + lane] = a + segb[0];
  } else if (lane < 32) {
    float a = 0.f;
#pragma unroll
    for (int i = 0; i < 16; ++i) a += sdis[lane - 16][i];
    odisp[m0 + lane - 16] = a + disb[0];
  }
}

// ---------------- pool: weighted max over 32 nbrs -> split-bf16 fin[416] ------
__global__ __launch_bounds__(256) void k_pool(const float* __restrict__ Yf,
                                              const float* __restrict__ Yfp,
                                              const float* __restrict__ feat,
                                              const float* __restrict__ pf,
                                              const int* __restrict__ idx,
                                              const float* __restrict__ w,
                                              unsigned short* __restrict__ finh,
                                              unsigned short* __restrict__ finl) {
  int n = blockIdx.x;
  int tid = threadIdx.x;
  __shared__ int sj[32];
  __shared__ float sw[32];
  if (tid < 32) { sj[tid] = idx[n*32+tid]; sw[tid] = w[n*32+tid]; }
  __syncthreads();
#define WRS(pos, val) { float v_ = (val); unsigned short h_ = f2bf(v_); \
    finh[(size_t)n*416 + (pos)] = h_; finl[(size_t)n*416 + (pos)] = f2bf(v_ - bf2f(h_)); }
  if (tid < 128) {
    int c = tid;
    float acc = -INFINITY;
#pragma unroll 8
    for (int k = 0; k < 32; ++k) acc = fmaxf(acc, sw[k] * Yfp[(size_t)sj[k]*128 + c]);
    WRS(c, lrelu(acc));                       // fp  [0,128)
    WRS(288 + c, lrelu(pf[n*128 + c]));       // pf  [288,416)
    if (c < 32) WRS(128 + c, lrelu(feat[n*32 + c]));  // feat [128,160)
  } else {
    int c = tid - 128;
    float acc = -INFINITY;
#pragma unroll 8
    for (int k = 0; k < 32; ++k) acc = fmaxf(acc, sw[k] * Yf[(size_t)sj[k]*128 + c]);
    WRS(160 + c, lrelu(acc));                 // f   [160,288)
  }
}

// ---------------- dis_center softmax ------------------------------------------
__global__ __launch_bounds__(1024) void k_discenter(const float* __restrict__ cloud,
                                                    const float* __restrict__ tvec,
                                                    float* __restrict__ dc) {
  __shared__ float sred[16];
  __shared__ float sbc[2];
  int tid = threadIdx.x;
  float tx = tvec[0], ty = tvec[1], tz = tvec[2];
  float v[8];
#pragma unroll
  for (int i = 0; i < 8; ++i) {
    int n = i*1024 + tid;
    float ax = cloud[n*3+0] + tx, ay = cloud[n*3+1] + ty, az = cloud[n*3+2] + tz;
    v[i] = sqrtf(ax*ax + ay*ay + az*az);
  }
  float m = v[0];
#pragma unroll
  for (int i = 1; i < 8; ++i) m = fmaxf(m, v[i]);
#pragma unroll
  for (int o = 1; o < 64; o <<= 1) m = fmaxf(m, __shfl_xor(m, o, 64));
  if ((tid & 63) == 0) sred[tid >> 6] = m;
  __syncthreads();
  if (tid == 0) {
    float mm = sred[0];
    for (int i = 1; i < 16; ++i) mm = fmaxf(mm, sred[i]);
    sbc[0] = mm;
  }
  __syncthreads();
  float gm = sbc[0];
  float e[8]; float s = 0.f;
#pragma unroll
  for (int i = 0; i < 8; ++i) { e[i] = expf(v[i] - gm); s += e[i]; }
#pragma unroll
  for (int o = 1; o < 64; o <<= 1) s += __shfl_xor(s, o, 64);
  __syncthreads();
  if ((tid & 63) == 0) sred[tid >> 6] = s;
  __syncthreads();
  if (tid == 0) {
    float ss = 0.f;
    for (int i = 0; i < 16; ++i) ss += sred[i];
    sbc[1] = ss;
  }
  __syncthreads();
  float gs = sbc[1];
#pragma unroll
  for (int i = 0; i < 8; ++i) dc[i*1024 + tid] = e[i] / gs;
}

// ---------------- g = sum_n fused[n]*dc[n]*seg[n] ------------------------------
__global__ __launch_bounds__(256) void k_g(const float* __restrict__ fused,
                                           const float* __restrict__ dc,
                                           const float* __restrict__ seg,
                                           float* __restrict__ g) {
  __shared__ float sbuf[256];
  int tid = threadIdx.x;
  int c = tid & 127, h = tid >> 7;
  float acc = 0.f;
  for (int r = 0; r < 128; ++r) {
    int n = blockIdx.x*256 + r*2 + h;
    acc += fused[(size_t)n*128 + c] * dc[n] * seg[n];
  }
  sbuf[tid] = acc;
  __syncthreads();
  if (tid < 128) atomicAdd(&g[c], sbuf[tid] + sbuf[tid+128]);
}

// ---------------- keypoint MLP 128->90->64->24 ---------------------------------
__global__ __launch_bounds__(128) void k_kp(const float* __restrict__ g,
                                            const float* __restrict__ l1w, const float* __restrict__ l1b,
                                            const float* __restrict__ l2w, const float* __restrict__ l2b,
                                            const float* __restrict__ l3w, const float* __restrict__ l3b,
                                            float* __restrict__ outp) {
  __shared__ float sg[128], s1[90], s2[64];
  int tid = threadIdx.x;
  sg[tid] = g[tid];
  __syncthreads();
  if (tid < 90) {
    float a = l1b[tid];
    for (int i = 0; i < 128; ++i) a += sg[i]*l1w[tid*128+i];
    s1[tid] = lrelu(a);
  }
  __syncthreads();
  if (tid < 64) {
    float a = l2b[tid];
    for (int i = 0; i < 90; ++i) a += s1[i]*l2w[tid*90+i];
    s2[tid] = lrelu(a);
  }
  __syncthreads();
  if (tid < 24) {
    float a = l3b[tid];
    for (int i = 0; i < 64; ++i) a += s2[i]*l3w[tid*64+i];
    outp[tid] = a;
  }
}

extern "C" void kernel_launch(void* const* d_in, const int* in_sizes, int n_in,
                              void* d_out, int out_size, void* d_ws, size_t ws_size,
                              hipStream_t stream) {
  const float* seg      = (const float*)d_in[0];
  const float* img      = (const float*)d_in[1];
  const float* cloud    = (const float*)d_in[2];
  const float* tvec     = (const float*)d_in[3];
  const int*   choose   = (const int*)d_in[4];
  const float* pconv1_w = (const float*)d_in[5];
  const float* pconv1_b = (const float*)d_in[6];
  const float* pconv2_w = (const float*)d_in[7];
  const float* pconv2_b = (const float*)d_in[8];
  const float* conv1_w  = (const float*)d_in[9];
  const float* conv1_b  = (const float*)d_in[10];
  const float* conv2_w  = (const float*)d_in[11];
  const float* conv2_b  = (const float*)d_in[12];
  const float* psconv1_w= (const float*)d_in[13];
  const float* psconv1_b= (const float*)d_in[14];
  const float* psconv2_w= (const float*)d_in[15];
  const float* psconv2_b= (const float*)d_in[16];
  const float* final_w  = (const float*)d_in[17];
  const float* final_b  = (const float*)d_in[18];
  const float* seg1_w   = (const float*)d_in[19];
  const float* seg1_b   = (const float*)d_in[20];
  const float* seg2_w   = (const float*)d_in[21];
  const float* seg2_b   = (const float*)d_in[22];
  const float* seg3_w   = (const float*)d_in[23];
  const float* seg3_b   = (const float*)d_in[24];
  const float* dis1_w   = (const float*)d_in[25];
  const float* dis1_b   = (const float*)d_in[26];
  const float* dis2_w   = (const float*)d_in[27];
  const float* dis2_b   = (const float*)d_in[28];
  const float* dis3_w   = (const float*)d_in[29];
  const float* dis3_b   = (const float*)d_in[30];
  const float* lin1_w   = (const float*)d_in[31];
  const float* lin1_b   = (const float*)d_in[32];
  const float* lin2_w   = (const float*)d_in[33];
  const float* lin2_b   = (const float*)d_in[34];
  const float* lin3_w   = (const float*)d_in[35];
  const float* lin3_b   = (const float*)d_in[36];

  float* out = (float*)d_out;
  float* ws  = (float*)d_ws;

  // workspace layout (float offsets; short planes cast from float regions)
  float* c4     = ws + 0;          // 32768
  float* feat   = ws + 32768;      // 262144
  unsigned short* feat_h = (unsigned short*)(ws + 294912);  // 131072 f
  unsigned short* feat_l = (unsigned short*)(ws + 425984);  // 131072 f
  unsigned short* h1h    = (unsigned short*)(ws + 557056);  // 262144 f (yh_h alias)
  unsigned short* h1l    = (unsigned short*)(ws + 819200);  // 262144 f (yh_l alias)
  float* pf     = ws + 1081344;    // 1048576 (fused_h/l planes alias later)
  unsigned short* pfh    = (unsigned short*)(ws + 2129920); // 524288 f (t1h alias)
  unsigned short* pfl    = (unsigned short*)(ws + 2654208); // 524288 f (t1l alias)
  float* Yf     = ws + 3178496;    // 1048576 (fused fp32 alias)
  unsigned short* phh    = (unsigned short*)(ws + 4227072); // 1048576 f (fin_h aliases ph region)
  unsigned short* phl    = (unsigned short*)(ws + 5275648); // 1048576 f
  float* Yfp    = ws + 6324224;    // 1048576
  int*   idx    = (int*)(ws + 7372800);   // 262144
  float* wsm    = ws + 7634944;    // 262144
  unsigned short* finl   = (unsigned short*)(ws + 7897088); // 1703936 f
  float* w3f    = ws + 9601024;    // 49152
  unsigned short* Wh     = (unsigned short*)(ws + 9650176); // 97280 f
  unsigned short* Wl     = (unsigned short*)(ws + 9747456); // 97280 f
  float* biasc  = ws + 9844736;    // 128
  float* W2pf   = ws + 9844864;    // 8192
  float* bias2c = ws + 9853056;    // 64
  float* g      = ws + 9853120;    // 128   -> total 9,853,248 floats (39.4 MB)

  // aliases (lifetimes verified against launch order)
  unsigned short* yhh    = h1h;                          // after pconv2 reads h1
  unsigned short* yhl    = h1l;
  unsigned short* finh   = phh;                          // after psconv2 reads ph
  float*          fused  = Yf;                           // after k_pool reads Yf
  unsigned short* fusedh = (unsigned short*)pf;          // after k_pool reads pf
  unsigned short* fusedl = (unsigned short*)(ws + 1081344 + 524288);
  unsigned short* t1h    = pfh;                          // after psconv1 reads pf planes
  unsigned short* t1l    = pfl;

  float* o_kp   = out;            // 24
  float* o_disp = out + 24;       // 8192
  float* o_dc   = out + 8216;     // 8192
  float* o_segp = out + 16408;    // 8192

  k_prep<<<1282, 256, 0, stream>>>(cloud, choose, img, seg1_w, dis1_w,
                                   seg1_b, dis1_b, seg2_w, dis2_w, seg2_b, dis2_b,
                                   c4, w3f, biasc, W2pf, bias2c, feat, feat_h, feat_l, g);
  k_split<<<(NSPLIT+255)/256, 256, 0, stream>>>(pconv2_w, conv1_w, conv2_w, psconv1_w,
                                                psconv2_w, final_w, w3f, W2pf, Wh, Wl);

  // point MLP: cloud -> h1(split) -> pf(f32+split)
  k_gemm_s<1><<<dim3(256,1), 256, 0, stream>>>(cloud, pconv1_w, pconv1_b, h1h, h1l, NPT, 64, 3);
  k_mg<64,8,0,2><<<512, 64, 0, stream>>>(h1h, h1l, Wh+OFF_PCONV2, Wl+OFF_PCONV2,
                                         pconv2_b, pf, pfh, pfl);

  k_knn<<<2048, 256, 0, stream>>>((const float4*)c4, idx, wsm);

  // per-point MLPs (gather-commuted)
  k_mg<32,4,1,1><<<512, 64, 0, stream>>>(feat_h, feat_l, Wh+OFF_CONV1, Wl+OFF_CONV1,
                                         conv1_b, nullptr, yhh, yhl);
  k_mg<64,8,0,0><<<512, 64, 0, stream>>>(yhh, yhl, Wh+OFF_CONV2, Wl+OFF_CONV2,
                                         conv2_b, Yf, nullptr, nullptr);
  k_mg<128,16,1,1><<<512, 64, 0, stream>>>(pfh, pfl, Wh+OFF_PSCONV1, Wl+OFF_PSCONV1,
                                           psconv1_b, nullptr, phh, phl);
  k_mg<256,8,0,0><<<512, 64, 0, stream>>>(phh, phl, Wh+OFF_PSCONV2, Wl+OFF_PSCONV2,
                                          psconv2_b, Yfp, nullptr, nullptr);

  k_pool<<<NPT, 256, 0, stream>>>(Yf, Yfp, feat, pf, idx, wsm, finh, finl);

  k_mg<416,8,0,2><<<512, 64, 0, stream>>>(finh, finl, Wh+OFF_FINAL, Wl+OFF_FINAL,
                                          final_b, fused, fusedh, fusedl);

  k_mg_c3<<<512, 64, 0, stream>>>(fusedh, fusedl, Wh+OFF_W3, Wl+OFF_W3, biasc, t1h, t1l);
  k_mg_head<<<512, 64, 0, stream>>>(t1h, t1l, Wh+OFF_W2P, Wl+OFF_W2P, bias2c,
                                    seg3_w, seg3_b, dis3_w, dis3_b, o_segp, o_disp);

  k_discenter<<<1, 1024, 0, stream>>>(cloud, tvec, o_dc);

  k_g<<<32, 256, 0, stream>>>(fused, o_dc, seg, g);
  k_kp<<<1, 128, 0, stream>>>(g, lin1_w, lin1_b, lin2_w, lin2_b, lin3_w, lin3_b, o_kp);

  (void)in_sizes; (void)n_in; (void)out_size; (void)ws_size;
}

// Round 5
// 364.402 us; speedup vs baseline: 1.7570x; 1.0068x over previous
//
#include <hip/hip_runtime.h>
#include <math.h>

#define NPT 8192
#define HWIMG 19200
#define KCAP 128

using short8 = __attribute__((ext_vector_type(8))) short;
using f32x4  = __attribute__((ext_vector_type(4))) float;

__device__ __forceinline__ float lrelu(float x) { return x > 0.f ? x : 0.01f * x; }
__device__ __forceinline__ unsigned short f2bf(float v) {
  unsigned u = __float_as_uint(v);
  return (unsigned short)((u + 0x7fffu + ((u >> 16) & 1u)) >> 16);
}
__device__ __forceinline__ float bf2f(unsigned short h) {
  return __uint_as_float(((unsigned)h) << 16);
}
__device__ __forceinline__ void split2(float v, unsigned short& h, unsigned short& l) {
  h = f2bf(v);
  l = f2bf(v - bf2f(h));
}
// split-bf16 3-term MFMA: acc += Ah*Wh + Al*Wh + Ah*Wl  (~1e-5 rel accuracy)
__device__ __forceinline__ void mfma3(f32x4& acc, short8 ah, short8 al, short8 wh, short8 wl) {
  acc = __builtin_amdgcn_mfma_f32_16x16x32_bf16(ah, wh, acc, 0, 0, 0);
  acc = __builtin_amdgcn_mfma_f32_16x16x32_bf16(al, wh, acc, 0, 0, 0);
  acc = __builtin_amdgcn_mfma_f32_16x16x32_bf16(ah, wl, acc, 0, 0, 0);
}

// weight-plane segment offsets (in shorts)
#define OFF_PCONV2  0
#define OFF_CONV1   8192
#define OFF_CONV2   10240
#define OFF_PSCONV1 18432
#define OFF_PSCONV2 51200
#define OFF_FINAL   83968
#define OFF_W3      137216
#define OFF_W2P     186368
#define NSPLIT      194560

// ---------------- prep: everything init (one launch) ---------------------------
// segments: c4(8192) | w3 split(49152) | biasc(128) | W2p split(8192) |
//           bias2c(64) | g+cnt(129) | feat gather+split(262144) | wsplit(137216)
__global__ void k_prep(const float* __restrict__ cloud, const int* __restrict__ choose,
                       const float* __restrict__ img,
                       const float* __restrict__ seg1_w, const float* __restrict__ dis1_w,
                       const float* __restrict__ seg1_b, const float* __restrict__ dis1_b,
                       const float* __restrict__ seg2_w, const float* __restrict__ dis2_w,
                       const float* __restrict__ seg2_b, const float* __restrict__ dis2_b,
                       const float* __restrict__ pconv2_w, const float* __restrict__ conv1_w,
                       const float* __restrict__ conv2_w, const float* __restrict__ psconv1_w,
                       const float* __restrict__ psconv2_w, const float* __restrict__ final_w,
                       float* __restrict__ c4, float* __restrict__ biasc,
                       float* __restrict__ bias2c, float* __restrict__ g,
                       float* __restrict__ feat, unsigned short* __restrict__ feat_h,
                       unsigned short* __restrict__ feat_l,
                       unsigned short* __restrict__ Wh, unsigned short* __restrict__ Wl) {
  int i = blockIdx.x * blockDim.x + threadIdx.x;
  if (i < NPT) {
    float x = cloud[i*3+0], y = cloud[i*3+1], z = cloud[i*3+2];
    float4 v; v.x = x; v.y = y; v.z = z; v.w = x*x + y*y + z*z;  // w = |c|^2 for dot-form knn
    ((float4*)c4)[i] = v;
  }
  {
    int j = i - NPT;                       // conv3 weight transpose + split
    if (j >= 0 && j < 49152) {
      int h = j / 24576, r = j - h*24576, o = r / 384, k = r - o*384;
      int t = k >> 7, c = k & 127;
      float v = (h ? dis1_w : seg1_w)[o*384 + c*3 + t];
      unsigned short hh, ll; split2(v, hh, ll);
      Wh[OFF_W3 + j] = hh; Wl[OFF_W3 + j] = ll;
    }
  }
  { int j = i - (NPT + 49152); if (j >= 0 && j < 128) biasc[j] = (j < 64) ? seg1_b[j] : dis1_b[j-64]; }
  {
    int j = i - (NPT + 49152 + 128);       // W2p block-diagonal + split
    if (j >= 0 && j < 8192) {
      int o = j >> 7, c = j & 127;
      float v = 0.f;
      if (o < 32) { if (c < 64) v = seg2_w[o*64 + c]; }
      else        { if (c >= 64) v = dis2_w[(o-32)*64 + (c-64)]; }
      unsigned short hh, ll; split2(v, hh, ll);
      Wh[OFF_W2P + j] = hh; Wl[OFF_W2P + j] = ll;
    }
  }
  { int j = i - (NPT + 49152 + 128 + 8192); if (j >= 0 && j < 64) bias2c[j] = (j < 32) ? seg2_b[j] : dis2_b[j-32]; }
  { int j = i - (NPT + 49152 + 128 + 8192 + 64); if (j >= 0 && j < 129) g[j] = 0.f; }  // g + counter
  {
    int j = i - (NPT + 49152 + 128 + 8192 + 64 + 129);
    if (j >= 0 && j < NPT*32) {
      int n = j >> 5, ch = j & 31;
      float v = img[ch*HWIMG + choose[n]];
      feat[j] = v;
      unsigned short hh, ll; split2(v, hh, ll);
      feat_h[j] = hh; feat_l[j] = ll;
    }
  }
  {
    int j = i - (NPT + 49152 + 128 + 8192 + 64 + 129 + NPT*32);
    if (j >= 0 && j < OFF_W3) {
      float v;
      if      (j < OFF_CONV1)   v = pconv2_w[j];
      else if (j < OFF_CONV2)   v = conv1_w[j - OFF_CONV1];
      else if (j < OFF_PSCONV1) v = conv2_w[j - OFF_CONV2];
      else if (j < OFF_PSCONV2) v = psconv1_w[j - OFF_PSCONV1];
      else if (j < OFF_FINAL)   v = psconv2_w[j - OFF_PSCONV2];
      else                      v = final_w[j - OFF_FINAL];
      unsigned short hh, ll; split2(v, hh, ll);
      Wh[j] = hh; Wl[j] = ll;
    }
  }
}
#define PREP_TOTAL (NPT + 49152 + 128 + 8192 + 64 + 129 + NPT*32 + OFF_W3)

// ---------------- KNN (dot-form prune, exact select) + dis_center block --------
__device__ __forceinline__ unsigned long long bsort64(unsigned long long key, int lane) {
#pragma unroll
  for (int k = 2; k <= 64; k <<= 1) {
#pragma unroll
    for (int j = k >> 1; j > 0; j >>= 1) {
      unsigned long long o = __shfl_xor(key, j, 64);
      bool keepmin = (((lane & j) == 0) == ((lane & k) == 0));
      bool omin = o < key;
      key = (omin == keepmin) ? o : key;
    }
  }
  return key;
}
__device__ __forceinline__ unsigned long long bmerge64(unsigned long long key, int lane) {
#pragma unroll
  for (int j = 32; j > 0; j >>= 1) {
    unsigned long long o = __shfl_xor(key, j, 64);
    bool keepmin = ((lane & j) == 0);
    bool omin = o < key;
    key = (omin == keepmin) ? o : key;
  }
  return key;
}

__global__ __launch_bounds__(256) void k_knn(const float4* __restrict__ c4,
                                             int* __restrict__ idxo, float* __restrict__ wo,
                                             const float* __restrict__ cloud,
                                             const float* __restrict__ tvec,
                                             float* __restrict__ dc) {
  int tid = threadIdx.x, lane = tid & 63, wv = tid >> 6;
  if (blockIdx.x == NPT/4) {
    // ---- dis_center softmax (independent work folded in as one extra block) ----
    __shared__ float sred[4];
    float tx = tvec[0], ty = tvec[1], tz = tvec[2];
    float v[32];
    float m = -INFINITY;
#pragma unroll
    for (int i2 = 0; i2 < 32; ++i2) {
      int n = i2*256 + tid;
      float ax = cloud[n*3+0] + tx, ay = cloud[n*3+1] + ty, az = cloud[n*3+2] + tz;
      v[i2] = sqrtf(ax*ax + ay*ay + az*az);
      m = fmaxf(m, v[i2]);
    }
#pragma unroll
    for (int o = 1; o < 64; o <<= 1) m = fmaxf(m, __shfl_xor(m, o, 64));
    if (lane == 0) sred[wv] = m;
    __syncthreads();
    m = fmaxf(fmaxf(sred[0], sred[1]), fmaxf(sred[2], sred[3]));
    __syncthreads();
    float s = 0.f;
#pragma unroll
    for (int i2 = 0; i2 < 32; ++i2) { v[i2] = expf(v[i2] - m); s += v[i2]; }
#pragma unroll
    for (int o = 1; o < 64; o <<= 1) s += __shfl_xor(s, o, 64);
    if (lane == 0) sred[wv] = s;
    __syncthreads();
    s = sred[0] + sred[1] + sred[2] + sred[3];
#pragma unroll
    for (int i2 = 0; i2 < 32; ++i2) dc[i2*256 + tid] = v[i2] / s;
    return;
  }
  __shared__ float smin[4][256];
  __shared__ float sT[4];
  __shared__ float sd[4][KCAP];
  __shared__ int   sj[4][KCAP];
  __shared__ int   scnt[4];
  int q0 = blockIdx.x * 4;
  float4 p0 = c4[q0], p1 = c4[q0+1], p2 = c4[q0+2], p3 = c4[q0+3];
  // dot-form: d = |p|^2 + |q|^2 - 2 p.q  (|.|^2 cached in .w)
  float p0x = -2.f*p0.x, p0y = -2.f*p0.y, p0z = -2.f*p0.z;
  float p1x = -2.f*p1.x, p1y = -2.f*p1.y, p1z = -2.f*p1.z;
  float p2x = -2.f*p2.x, p2y = -2.f*p2.y, p2z = -2.f*p2.z;
  float p3x = -2.f*p3.x, p3y = -2.f*p3.y, p3z = -2.f*p3.z;
#define DDOT(PX,PY,PZ,PW,CJ) fmaf(PX,(CJ).x, fmaf(PY,(CJ).y, fmaf(PZ,(CJ).z, PW + (CJ).w)))
  float m0 = INFINITY, m1 = INFINITY, m2 = INFINITY, m3 = INFINITY;
  for (int t = 0; t < 32; ++t) {
    float4 cj = c4[t*256 + tid];
    m0 = fminf(m0, DDOT(p0x,p0y,p0z,p0.w,cj));
    m1 = fminf(m1, DDOT(p1x,p1y,p1z,p1.w,cj));
    m2 = fminf(m2, DDOT(p2x,p2y,p2z,p2.w,cj));
    m3 = fminf(m3, DDOT(p3x,p3y,p3z,p3.w,cj));
  }
  smin[0][tid] = m0; smin[1][tid] = m1; smin[2][tid] = m2; smin[3][tid] = m3;
  if (tid < 4) scnt[tid] = 0;
  __syncthreads();
  // wave wv: T_ub = 32nd smallest of 256 per-thread dot-mins (valid upper bound)
  {
    float4 vv = *(const float4*)&smin[wv][lane*4];
    float v0 = vv.x, v1 = vv.y, v2 = vv.z, v3 = vv.w;
#define CSV(a,b) { if (b < a) { float t_ = a; a = b; b = t_; } }
    CSV(v0,v2) CSV(v1,v3) CSV(v0,v1) CSV(v2,v3) CSV(v1,v2)
    float T = 0.f;
    for (int it = 0; it < 32; ++it) {
      float mn = v0;
#pragma unroll
      for (int o = 1; o < 64; o <<= 1) mn = fminf(mn, __shfl_xor(mn, o, 64));
      T = mn;
      if (v0 == mn) { v0 = v1; v1 = v2; v2 = v3; v3 = INFINITY; }
    }
    // inflate by 2*delta (dot-form abs error bound) so exact top-32 always passes
    if (lane == 0) sT[wv] = T * (1.f + 2e-5f) + 4e-5f;
  }
  __syncthreads();
  float T0 = sT[0], T1 = sT[1], T2 = sT[2], T3 = sT[3];
  // filter pass: dot-form compare; survivors get exact difference-form distance
  for (int t = 0; t < 32; ++t) {
    int j = t*256 + tid;
    float4 cj = c4[j];
    float d;
#define APPEND(Q, P) { \
    float dx_ = (P).x-cj.x, dy_ = (P).y-cj.y, dz_ = (P).z-cj.z; \
    float de_ = dx_*dx_ + dy_*dy_ + dz_*dz_; \
    int p_ = atomicAdd(&scnt[Q],1); if (p_ < KCAP) { sd[Q][p_] = de_; sj[Q][p_] = j; } }
    d = DDOT(p0x,p0y,p0z,p0.w,cj); if (d <= T0) APPEND(0, p0);
    d = DDOT(p1x,p1y,p1z,p1.w,cj); if (d <= T1) APPEND(1, p1);
    d = DDOT(p2x,p2y,p2z,p2.w,cj); if (d <= T2) APPEND(2, p2);
    d = DDOT(p3x,p3y,p3z,p3.w,cj); if (d <= T3) APPEND(3, p3);
  }
  __syncthreads();
  // wave wv: exact top-32 among survivors via bitonic sort (+merge)
  int M = scnt[wv]; if (M > KCAP) M = KCAP;
  unsigned long long key = (lane < M)
      ? (((unsigned long long)__float_as_uint(sd[wv][lane]) << 32) | (unsigned)sj[wv][lane])
      : ~0ull;
  key = bsort64(key, lane);
  for (int base = 64; base < M; base += 64) {
    unsigned long long nk = (base + lane < M)
        ? (((unsigned long long)__float_as_uint(sd[wv][base+lane]) << 32) | (unsigned)sj[wv][base+lane])
        : ~0ull;
    nk = bsort64(nk, lane);
    nk = __shfl_xor(nk, 63, 64);
    key = key < nk ? key : nk;
    key = bmerge64(key, lane);
  }
  float dsel = __uint_as_float((unsigned)(key >> 32));
  int   jsel = (int)(unsigned)(key & 0xffffffffu);
  float v = -sqrtf(dsel);
  float mx = v;
#pragma unroll
  for (int o = 1; o < 32; o <<= 1) mx = fmaxf(mx, __shfl_xor(mx, o, 64));
  float e = expf(v - mx);
  float s = e;
#pragma unroll
  for (int o = 1; o < 32; o <<= 1) s += __shfl_xor(s, o, 64);
  if (lane < 32) {
    int q = q0 + wv;
    wo[q*32 + lane] = e / s;
    idxo[q*32 + lane] = jsel;
  }
}

// ---------------- fused MLP chains, one wave per 16 rows -----------------------
// blocks [0,512): pconv1->pconv2->psconv1->psconv2 -> pf(f32), Yfp(f32)
// blocks [512,1024): conv1->conv2 -> Yf(f32)
__global__ __launch_bounds__(64) void k_chain(const float4* __restrict__ c4,
                                              const float* __restrict__ pconv1_w, const float* __restrict__ pconv1_b,
                                              const float* __restrict__ pconv2_b, const float* __restrict__ psconv1_b,
                                              const float* __restrict__ psconv2_b,
                                              const unsigned short* __restrict__ feat_h,
                                              const unsigned short* __restrict__ feat_l,
                                              const float* __restrict__ conv1_b, const float* __restrict__ conv2_b,
                                              const unsigned short* __restrict__ Wh,
                                              const unsigned short* __restrict__ Wl,
                                              float* __restrict__ pf, float* __restrict__ Yfp,
                                              float* __restrict__ Yf) {
  // LDS staging: pf tile @0 stride 136 | ph tile @2176 stride 264 | feat-chain yh @0 stride 72
  __shared__ unsigned short sh_h[6400], sh_l[6400];
  int lane = threadIdx.x, mr = lane & 15, q = lane >> 4;
  if (blockIdx.x < 512) {
    int m0 = blockIdx.x * 16;
    // ---- stage 1: pconv1 (K=3) computed directly in A-frag ownership ----
    float4 cp = c4[m0 + mr];
    short8 ah0, al0, ah1, al1;
#pragma unroll
    for (int j = 0; j < 8; ++j) {
      int c0 = q*8 + j, c1 = 32 + q*8 + j;
      float v0 = lrelu(fmaf(cp.x, pconv1_w[c0*3+0], fmaf(cp.y, pconv1_w[c0*3+1],
                        fmaf(cp.z, pconv1_w[c0*3+2], pconv1_b[c0]))));
      float v1 = lrelu(fmaf(cp.x, pconv1_w[c1*3+0], fmaf(cp.y, pconv1_w[c1*3+1],
                        fmaf(cp.z, pconv1_w[c1*3+2], pconv1_b[c1]))));
      unsigned short hh, ll;
      split2(v0, hh, ll); ah0[j] = (short)hh; al0[j] = (short)ll;
      split2(v1, hh, ll); ah1[j] = (short)hh; al1[j] = (short)ll;
    }
    // ---- stage 2: pconv2 (K=64, N=128) ----
    f32x4 acc[8];
#pragma unroll
    for (int t = 0; t < 8; ++t) { f32x4 z = {0.f,0.f,0.f,0.f}; acc[t] = z; }
    const unsigned short* W2h = Wh + OFF_PCONV2;
    const unsigned short* W2l = Wl + OFF_PCONV2;
#pragma unroll
    for (int t = 0; t < 8; ++t) {
      int wr = (t*16 + mr)*64 + q*8;
      mfma3(acc[t], ah0, al0, *(const short8*)(W2h + wr), *(const short8*)(W2l + wr));
      mfma3(acc[t], ah1, al1, *(const short8*)(W2h + wr + 32), *(const short8*)(W2l + wr + 32));
    }
#pragma unroll
    for (int t = 0; t < 8; ++t) {
      int n = t*16 + mr;
      float b = pconv2_b[n];
#pragma unroll
      for (int r = 0; r < 4; ++r) {
        int row = q*4 + r;
        float v = acc[t][r] + b;
        pf[(size_t)(m0+row)*128 + n] = v;
        unsigned short hh, ll; split2(v, hh, ll);
        sh_h[row*136 + n] = hh; sh_l[row*136 + n] = ll;
      }
    }
    __syncthreads();
    // ---- stage 3: psconv1 (K=128, N=256) ----
    f32x4 acc2[16];
#pragma unroll
    for (int t = 0; t < 16; ++t) { f32x4 z = {0.f,0.f,0.f,0.f}; acc2[t] = z; }
    const unsigned short* W3h = Wh + OFF_PSCONV1;
    const unsigned short* W3l = Wl + OFF_PSCONV1;
#pragma unroll
    for (int ks = 0; ks < 4; ++ks) {
      short8 ah = *(const short8*)&sh_h[mr*136 + q*8 + ks*32];
      short8 al = *(const short8*)&sh_l[mr*136 + q*8 + ks*32];
#pragma unroll
      for (int t = 0; t < 16; ++t) {
        int wr = (t*16 + mr)*128 + q*8 + ks*32;
        mfma3(acc2[t], ah, al, *(const short8*)(W3h + wr), *(const short8*)(W3l + wr));
      }
    }
    __syncthreads();
#pragma unroll
    for (int t = 0; t < 16; ++t) {
      int n = t*16 + mr;
      float b = psconv1_b[n];
#pragma unroll
      for (int r = 0; r < 4; ++r) {
        int row = q*4 + r;
        float v = lrelu(acc2[t][r] + b);
        unsigned short hh, ll; split2(v, hh, ll);
        sh_h[2176 + row*264 + n] = hh; sh_l[2176 + row*264 + n] = ll;
      }
    }
    __syncthreads();
    // ---- stage 4: psconv2 (K=256, N=128) -> Yfp ----
    f32x4 acc3[8];
#pragma unroll
    for (int t = 0; t < 8; ++t) { f32x4 z = {0.f,0.f,0.f,0.f}; acc3[t] = z; }
    const unsigned short* W4h = Wh + OFF_PSCONV2;
    const unsigned short* W4l = Wl + OFF_PSCONV2;
#pragma unroll
    for (int ks = 0; ks < 8; ++ks) {
      short8 ah = *(const short8*)&sh_h[2176 + mr*264 + q*8 + ks*32];
      short8 al = *(const short8*)&sh_l[2176 + mr*264 + q*8 + ks*32];
#pragma unroll
      for (int t = 0; t < 8; ++t) {
        int wr = (t*16 + mr)*256 + q*8 + ks*32;
        mfma3(acc3[t], ah, al, *(const short8*)(W4h + wr), *(const short8*)(W4l + wr));
      }
    }
#pragma unroll
    for (int t = 0; t < 8; ++t) {
      int n = t*16 + mr;
      float b = psconv2_b[n];
#pragma unroll
      for (int r = 0; r < 4; ++r)
        Yfp[(size_t)(m0 + q*4 + r)*128 + n] = acc3[t][r] + b;
    }
  } else {
    int m0 = (blockIdx.x - 512) * 16;
    // ---- conv1 (K=32, N=64) ----
    short8 ah = *(const short8*)(feat_h + (size_t)(m0+mr)*32 + q*8);
    short8 al = *(const short8*)(feat_l + (size_t)(m0+mr)*32 + q*8);
    f32x4 acc[4];
#pragma unroll
    for (int t = 0; t < 4; ++t) { f32x4 z = {0.f,0.f,0.f,0.f}; acc[t] = z; }
    const unsigned short* W1h = Wh + OFF_CONV1;
    const unsigned short* W1l = Wl + OFF_CONV1;
#pragma unroll
    for (int t = 0; t < 4; ++t) {
      int wr = (t*16 + mr)*32 + q*8;
      mfma3(acc[t], ah, al, *(const short8*)(W1h + wr), *(const short8*)(W1l + wr));
    }
#pragma unroll
    for (int t = 0; t < 4; ++t) {
      int n = t*16 + mr;
      float b = conv1_b[n];
#pragma unroll
      for (int r = 0; r < 4; ++r) {
        int row = q*4 + r;
        float v = lrelu(acc[t][r] + b);
        unsigned short hh, ll; split2(v, hh, ll);
        sh_h[row*72 + n] = hh; sh_l[row*72 + n] = ll;
      }
    }
    __syncthreads();
    // ---- conv2 (K=64, N=128) -> Yf ----
    f32x4 acc2[8];
#pragma unroll
    for (int t = 0; t < 8; ++t) { f32x4 z = {0.f,0.f,0.f,0.f}; acc2[t] = z; }
    const unsigned short* W2h = Wh + OFF_CONV2;
    const unsigned short* W2l = Wl + OFF_CONV2;
#pragma unroll
    for (int ks = 0; ks < 2; ++ks) {
      short8 a2 = *(const short8*)&sh_h[mr*72 + q*8 + ks*32];
      short8 a2l = *(const short8*)&sh_l[mr*72 + q*8 + ks*32];
#pragma unroll
      for (int t = 0; t < 8; ++t) {
        int wr = (t*16 + mr)*64 + q*8 + ks*32;
        mfma3(acc2[t], a2, a2l, *(const short8*)(W2h + wr), *(const short8*)(W2l + wr));
      }
    }
#pragma unroll
    for (int t = 0; t < 8; ++t) {
      int n = t*16 + mr;
      float b = conv2_b[n];
#pragma unroll
      for (int r = 0; r < 4; ++r)
        Yf[(size_t)(m0 + q*4 + r)*128 + n] = acc2[t][r] + b;
    }
  }
}

// ---------------- pool: weighted max over 32 nbrs -> split-bf16 fin[416] ------
__global__ __launch_bounds__(256) void k_pool(const float* __restrict__ Yf,
                                              const float* __restrict__ Yfp,
                                              const float* __restrict__ feat,
                                              const float* __restrict__ pf,
                                              const int* __restrict__ idx,
                                              const float* __restrict__ w,
                                              unsigned short* __restrict__ finh,
                                              unsigned short* __restrict__ finl) {
  int n = blockIdx.x;
  int tid = threadIdx.x;
  __shared__ int sj[32];
  __shared__ float sw[32];
  if (tid < 32) { sj[tid] = idx[n*32+tid]; sw[tid] = w[n*32+tid]; }
  __syncthreads();
#define WRS(pos, val) { float v_ = (val); unsigned short h_, l_; split2(v_, h_, l_); \
    finh[(size_t)n*416 + (pos)] = h_; finl[(size_t)n*416 + (pos)] = l_; }
  if (tid < 128) {
    int c = tid;
    float acc = -INFINITY;
#pragma unroll 8
    for (int k = 0; k < 32; ++k) acc = fmaxf(acc, sw[k] * Yfp[(size_t)sj[k]*128 + c]);
    WRS(c, lrelu(acc));                       // fp  [0,128)
    WRS(288 + c, lrelu(pf[n*128 + c]));       // pf  [288,416)
    if (c < 32) WRS(128 + c, lrelu(feat[n*32 + c]));  // feat [128,160)
  } else {
    int c = tid - 128;
    float acc = -INFINITY;
#pragma unroll 8
    for (int k = 0; k < 32; ++k) acc = fmaxf(acc, sw[k] * Yf[(size_t)sj[k]*128 + c]);
    WRS(160 + c, lrelu(acc));                 // f   [160,288)
  }
}

// ---------------- final MFMA GEMM (K=416, N=128) -> fused f32 + split ---------
__global__ __launch_bounds__(64) void k_final(const unsigned short* __restrict__ Ah,
                                              const unsigned short* __restrict__ Al,
                                              const unsigned short* __restrict__ Wh,
                                              const unsigned short* __restrict__ Wl,
                                              const float* __restrict__ bias,
                                              float* __restrict__ Cf,
                                              unsigned short* __restrict__ Ch,
                                              unsigned short* __restrict__ Cl) {
  int lane = threadIdx.x, mr = lane & 15, q = lane >> 4;
  int m0 = blockIdx.x * 16;
  f32x4 acc[8];
#pragma unroll
  for (int t = 0; t < 8; ++t) { f32x4 z = {0.f,0.f,0.f,0.f}; acc[t] = z; }
  const unsigned short* arh = Ah + (size_t)(m0 + mr) * 416 + q * 8;
  const unsigned short* arl = Al + (size_t)(m0 + mr) * 416 + q * 8;
#pragma unroll
  for (int ks = 0; ks < 13; ++ks) {
    short8 ah = *(const short8*)(arh + ks * 32);
    short8 al = *(const short8*)(arl + ks * 32);
#pragma unroll
    for (int t = 0; t < 8; ++t) {
      int wr = (t*16 + mr)*416 + q*8 + ks*32;
      mfma3(acc[t], ah, al, *(const short8*)(Wh + wr), *(const short8*)(Wl + wr));
    }
  }
#pragma unroll
  for (int t = 0; t < 8; ++t) {
    int n = t*16 + mr;
    float b = bias[n];
#pragma unroll
    for (int r = 0; r < 4; ++r) {
      int row = m0 + q*4 + r;
      float v = acc[t][r] + b;
      Cf[(size_t)row*128 + n] = v;
      unsigned short hh, ll; split2(v, hh, ll);
      Ch[(size_t)row*128 + n] = hh;
      Cl[(size_t)row*128 + n] = ll;
    }
  }
}

// ---------------- conv3 + head chain fused (t1 stays in LDS) ------------------
__global__ __launch_bounds__(64) void k_c3head(const unsigned short* __restrict__ Ah,
                                               const unsigned short* __restrict__ Al,
                                               const unsigned short* __restrict__ Wh,
                                               const unsigned short* __restrict__ Wl,
                                               const float* __restrict__ biasc,
                                               const float* __restrict__ bias2c,
                                               const float* __restrict__ segw, const float* __restrict__ segb,
                                               const float* __restrict__ disw, const float* __restrict__ disb,
                                               float* __restrict__ osegp, float* __restrict__ odisp) {
  __shared__ unsigned short t1h[2176], t1l[2176];
  __shared__ float sseg[16][17], sdis[16][17];
  int lane = threadIdx.x, mr = lane & 15, q = lane >> 4;
  int m0 = blockIdx.x * 16;
  // conv3 (K=384 via im2col taps, N=128: seg|dis)
  f32x4 acc[8];
#pragma unroll
  for (int t = 0; t < 8; ++t) { f32x4 z = {0.f,0.f,0.f,0.f}; acc[t] = z; }
  const unsigned short* W3h = Wh + OFF_W3;
  const unsigned short* W3l = Wl + OFF_W3;
#pragma unroll
  for (int ks = 0; ks < 12; ++ks) {
    int tap = ks >> 2;
    int kin = (ks & 3)*32 + q*8;
    int ar = m0 + mr + tap - 1;
    short8 ah = {0,0,0,0,0,0,0,0}, al = {0,0,0,0,0,0,0,0};
    if (ar >= 0 && ar < NPT) {
      ah = *(const short8*)(Ah + (size_t)ar*128 + kin);
      al = *(const short8*)(Al + (size_t)ar*128 + kin);
    }
#pragma unroll
    for (int t = 0; t < 8; ++t) {
      int wr = (t*16 + mr)*384 + ks*32 + q*8;
      mfma3(acc[t], ah, al, *(const short8*)(W3h + wr), *(const short8*)(W3l + wr));
    }
  }
#pragma unroll
  for (int t = 0; t < 8; ++t) {
    int n = t*16 + mr;
    float b = biasc[n];
#pragma unroll
    for (int r = 0; r < 4; ++r) {
      int row = q*4 + r;
      float v = lrelu(acc[t][r] + b);
      unsigned short hh, ll; split2(v, hh, ll);
      t1h[row*136 + n] = hh; t1l[row*136 + n] = ll;
    }
  }
  __syncthreads();
  // head GEMM (K=128, N=64 block-diag seg2|dis2) + fused 1-wide heads
  f32x4 acc2[4];
#pragma unroll
  for (int t = 0; t < 4; ++t) { f32x4 z = {0.f,0.f,0.f,0.f}; acc2[t] = z; }
  const unsigned short* WPh = Wh + OFF_W2P;
  const unsigned short* WPl = Wl + OFF_W2P;
#pragma unroll
  for (int ks = 0; ks < 4; ++ks) {
    short8 ah = *(const short8*)&t1h[mr*136 + q*8 + ks*32];
    short8 al = *(const short8*)&t1l[mr*136 + q*8 + ks*32];
#pragma unroll
    for (int t = 0; t < 4; ++t) {
      int wr = (t*16 + mr)*128 + q*8 + ks*32;
      mfma3(acc2[t], ah, al, *(const short8*)(WPh + wr), *(const short8*)(WPl + wr));
    }
  }
  float hs0 = segw[mr], hs1 = segw[16 + mr];
  float hd0 = disw[mr], hd1 = disw[16 + mr];
#pragma unroll
  for (int r = 0; r < 4; ++r) {
    float ss = lrelu(acc2[0][r] + bias2c[mr]) * hs0 + lrelu(acc2[1][r] + bias2c[16+mr]) * hs1;
    float ds = lrelu(acc2[2][r] + bias2c[32+mr]) * hd0 + lrelu(acc2[3][r] + bias2c[48+mr]) * hd1;
    sseg[q*4 + r][mr] = ss;
    sdis[q*4 + r][mr] = ds;
  }
  __syncthreads();
  if (lane < 16) {
    float a = 0.f;
#pragma unroll
    for (int i = 0; i < 16; ++i) a += sseg[lane][i];
    osegp[m0 + lane] = a + segb[0];
  } else if (lane < 32) {
    float a = 0.f;
#pragma unroll
    for (int i = 0; i < 16; ++i) a += sdis[lane - 16][i];
    odisp[m0 + lane - 16] = a + disb[0];
  }
}

// ---------------- g-reduction + keypoint MLP (counter-chained, one launch) ----
__global__ __launch_bounds__(256) void k_gkp(const float* __restrict__ fused,
                                             const float* __restrict__ dc,
                                             const float* __restrict__ seg,
                                             float* __restrict__ g,
                                             const float* __restrict__ l1w, const float* __restrict__ l1b,
                                             const float* __restrict__ l2w, const float* __restrict__ l2b,
                                             const float* __restrict__ l3w, const float* __restrict__ l3b,
                                             float* __restrict__ outp) {
  __shared__ float sbuf[256];
  __shared__ int slast;
  int tid = threadIdx.x;
  int c = tid & 127, h = tid >> 7;
  float acc = 0.f;
  for (int r = 0; r < 128; ++r) {
    int n = blockIdx.x*256 + r*2 + h;
    acc += fused[(size_t)n*128 + c] * dc[n] * seg[n];
  }
  sbuf[tid] = acc;
  __syncthreads();
  if (tid < 128) atomicAdd(&g[c], sbuf[tid] + sbuf[tid+128]);
  __threadfence();
  __syncthreads();
  if (tid == 0) slast = (atomicAdd((int*)(g + 128), 1) == 31);
  __syncthreads();
  if (!slast) return;
  // last block: read final g (device-scope atomic reads) and run the MLP
  __shared__ float sg[128], s1[90], s2[64];
  if (tid < 128) sg[tid] = atomicAdd(&g[tid], 0.f);
  __syncthreads();
  if (tid < 90) {
    float a = l1b[tid];
    for (int i = 0; i < 128; ++i) a += sg[i]*l1w[tid*128+i];
    s1[tid] = lrelu(a);
  }
  __syncthreads();
  if (tid < 64) {
    float a = l2b[tid];
    for (int i = 0; i < 90; ++i) a += s1[i]*l2w[tid*90+i];
    s2[tid] = lrelu(a);
  }
  __syncthreads();
  if (tid < 24) {
    float a = l3b[tid];
    for (int i = 0; i < 64; ++i) a += s2[i]*l3w[tid*64+i];
    outp[tid] = a;
  }
}

extern "C" void kernel_launch(void* const* d_in, const int* in_sizes, int n_in,
                              void* d_out, int out_size, void* d_ws, size_t ws_size,
                              hipStream_t stream) {
  const float* seg      = (const float*)d_in[0];
  const float* img      = (const float*)d_in[1];
  const float* cloud    = (const float*)d_in[2];
  const float* tvec     = (const float*)d_in[3];
  const int*   choose   = (const int*)d_in[4];
  const float* pconv1_w = (const float*)d_in[5];
  const float* pconv1_b = (const float*)d_in[6];
  const float* pconv2_w = (const float*)d_in[7];
  const float* pconv2_b = (const float*)d_in[8];
  const float* conv1_w  = (const float*)d_in[9];
  const float* conv1_b  = (const float*)d_in[10];
  const float* conv2_w  = (const float*)d_in[11];
  const float* conv2_b  = (const float*)d_in[12];
  const float* psconv1_w= (const float*)d_in[13];
  const float* psconv1_b= (const float*)d_in[14];
  const float* psconv2_w= (const float*)d_in[15];
  const float* psconv2_b= (const float*)d_in[16];
  const float* final_w  = (const float*)d_in[17];
  const float* final_b  = (const float*)d_in[18];
  const float* seg1_w   = (const float*)d_in[19];
  const float* seg1_b   = (const float*)d_in[20];
  const float* seg2_w   = (const float*)d_in[21];
  const float* seg2_b   = (const float*)d_in[22];
  const float* seg3_w   = (const float*)d_in[23];
  const float* seg3_b   = (const float*)d_in[24];
  const float* dis1_w   = (const float*)d_in[25];
  const float* dis1_b   = (const float*)d_in[26];
  const float* dis2_w   = (const float*)d_in[27];
  const float* dis2_b   = (const float*)d_in[28];
  const float* dis3_w   = (const float*)d_in[29];
  const float* dis3_b   = (const float*)d_in[30];
  const float* lin1_w   = (const float*)d_in[31];
  const float* lin1_b   = (const float*)d_in[32];
  const float* lin2_w   = (const float*)d_in[33];
  const float* lin2_b   = (const float*)d_in[34];
  const float* lin3_w   = (const float*)d_in[35];
  const float* lin3_b   = (const float*)d_in[36];

  float* out = (float*)d_out;
  float* ws  = (float*)d_ws;

  // workspace layout (float offsets), no aliasing
  float* c4     = ws + 0;          // 32768
  float* feat   = ws + 32768;      // 262144
  unsigned short* feat_h = (unsigned short*)(ws + 294912);   // 131072 f
  unsigned short* feat_l = (unsigned short*)(ws + 425984);   // 131072 f
  float* pf     = ws + 557056;     // 1048576
  float* Yf     = ws + 1605632;    // 1048576
  float* Yfp    = ws + 2654208;    // 1048576
  int*   idx    = (int*)(ws + 3702784);   // 262144
  float* wsm    = ws + 3964928;    // 262144
  unsigned short* finh  = (unsigned short*)(ws + 4227072);   // 1703936 f
  unsigned short* finl  = (unsigned short*)(ws + 5931008);   // 1703936 f
  float* fused  = ws + 7634944;    // 1048576
  unsigned short* fusedh = (unsigned short*)(ws + 8683520);  // 524288 f
  unsigned short* fusedl = (unsigned short*)(ws + 9207808);  // 524288 f
  unsigned short* Wh    = (unsigned short*)(ws + 9732096);   // 97280 f
  unsigned short* Wl    = (unsigned short*)(ws + 9829376);   // 97280 f
  float* biasc  = ws + 9926656;    // 128
  float* bias2c = ws + 9926784;    // 64
  float* g      = ws + 9926848;    // 129 (g[128] is the int counter) -> 9,926,977 f (39.7 MB)

  float* o_kp   = out;             // 24
  float* o_disp = out + 24;        // 8192
  float* o_dc   = out + 8216;      // 8192
  float* o_segp = out + 16408;     // 8192

  k_prep<<<(PREP_TOTAL + 255)/256, 256, 0, stream>>>(
      cloud, choose, img, seg1_w, dis1_w, seg1_b, dis1_b,
      seg2_w, dis2_w, seg2_b, dis2_b,
      pconv2_w, conv1_w, conv2_w, psconv1_w, psconv2_w, final_w,
      c4, biasc, bias2c, g, feat, feat_h, feat_l, Wh, Wl);

  k_knn<<<NPT/4 + 1, 256, 0, stream>>>((const float4*)c4, idx, wsm, cloud, tvec, o_dc);

  k_chain<<<1024, 64, 0, stream>>>(
      (const float4*)c4, pconv1_w, pconv1_b, pconv2_b, psconv1_b, psconv2_b,
      feat_h, feat_l, conv1_b, conv2_b, Wh, Wl, pf, Yfp, Yf);

  k_pool<<<NPT, 256, 0, stream>>>(Yf, Yfp, feat, pf, idx, wsm, finh, finl);

  k_final<<<512, 64, 0, stream>>>(finh, finl, Wh + OFF_FINAL, Wl + OFF_FINAL,
                                  final_b, fused, fusedh, fusedl);

  k_c3head<<<512, 64, 0, stream>>>(fusedh, fusedl, Wh, Wl, biasc, bias2c,
                                   seg3_w, seg3_b, dis3_w, dis3_b, o_segp, o_disp);

  k_gkp<<<32, 256, 0, stream>>>(fused, o_dc, seg, g,
                                lin1_w, lin1_b, lin2_w, lin2_b, lin3_w, lin3_b, o_kp);

  (void)in_sizes; (void)n_in; (void)out_size; (void)ws_size;
}

// Round 6
// 295.995 us; speedup vs baseline: 2.1630x; 1.2311x over previous
//
#include <hip/hip_runtime.h>
#include <math.h>

#define NPT 8192
#define HWIMG 19200
#define KCAP 128

using short8 = __attribute__((ext_vector_type(8))) short;
using f32x4  = __attribute__((ext_vector_type(4))) float;

__device__ __forceinline__ float lrelu(float x) { return x > 0.f ? x : 0.01f * x; }
__device__ __forceinline__ unsigned short f2bf(float v) {
  unsigned u = __float_as_uint(v);
  return (unsigned short)((u + 0x7fffu + ((u >> 16) & 1u)) >> 16);
}
__device__ __forceinline__ float bf2f(unsigned short h) {
  return __uint_as_float(((unsigned)h) << 16);
}
__device__ __forceinline__ void split2(float v, unsigned short& h, unsigned short& l) {
  h = f2bf(v);
  l = f2bf(v - bf2f(h));
}
// split-bf16 3-term MFMA: acc += Ah*Wh + Al*Wh + Ah*Wl  (~1e-5 rel accuracy)
__device__ __forceinline__ void mfma3(f32x4& acc, short8 ah, short8 al, short8 wh, short8 wl) {
  acc = __builtin_amdgcn_mfma_f32_16x16x32_bf16(ah, wh, acc, 0, 0, 0);
  acc = __builtin_amdgcn_mfma_f32_16x16x32_bf16(al, wh, acc, 0, 0, 0);
  acc = __builtin_amdgcn_mfma_f32_16x16x32_bf16(ah, wl, acc, 0, 0, 0);
}

// weight-plane segment offsets (in shorts)
#define OFF_PCONV2  0
#define OFF_CONV1   8192
#define OFF_CONV2   10240
#define OFF_PSCONV1 18432
#define OFF_PSCONV2 51200
#define OFF_FINAL   83968
#define OFF_W3      137216
#define OFF_W2P     186368
#define NSPLIT      194560

// ---------------- prep: everything init (one launch) ---------------------------
__global__ void k_prep(const float* __restrict__ cloud, const int* __restrict__ choose,
                       const float* __restrict__ img,
                       const float* __restrict__ seg1_w, const float* __restrict__ dis1_w,
                       const float* __restrict__ seg1_b, const float* __restrict__ dis1_b,
                       const float* __restrict__ seg2_w, const float* __restrict__ dis2_w,
                       const float* __restrict__ seg2_b, const float* __restrict__ dis2_b,
                       const float* __restrict__ pconv2_w, const float* __restrict__ conv1_w,
                       const float* __restrict__ conv2_w, const float* __restrict__ psconv1_w,
                       const float* __restrict__ psconv2_w, const float* __restrict__ final_w,
                       float* __restrict__ c4, float* __restrict__ biasc,
                       float* __restrict__ bias2c, float* __restrict__ g,
                       float* __restrict__ feat, unsigned short* __restrict__ feat_h,
                       unsigned short* __restrict__ feat_l,
                       unsigned short* __restrict__ Wh, unsigned short* __restrict__ Wl) {
  int i = blockIdx.x * blockDim.x + threadIdx.x;
  if (i < NPT) {
    float x = cloud[i*3+0], y = cloud[i*3+1], z = cloud[i*3+2];
    float4 v; v.x = x; v.y = y; v.z = z; v.w = x*x + y*y + z*z;  // w = |c|^2 for dot-form knn
    ((float4*)c4)[i] = v;
  }
  {
    int j = i - NPT;                       // conv3 weight transpose + split
    if (j >= 0 && j < 49152) {
      int h = j / 24576, r = j - h*24576, o = r / 384, k = r - o*384;
      int t = k >> 7, c = k & 127;
      float v = (h ? dis1_w : seg1_w)[o*384 + c*3 + t];
      unsigned short hh, ll; split2(v, hh, ll);
      Wh[OFF_W3 + j] = hh; Wl[OFF_W3 + j] = ll;
    }
  }
  { int j = i - (NPT + 49152); if (j >= 0 && j < 128) biasc[j] = (j < 64) ? seg1_b[j] : dis1_b[j-64]; }
  {
    int j = i - (NPT + 49152 + 128);       // W2p block-diagonal + split
    if (j >= 0 && j < 8192) {
      int o = j >> 7, c = j & 127;
      float v = 0.f;
      if (o < 32) { if (c < 64) v = seg2_w[o*64 + c]; }
      else        { if (c >= 64) v = dis2_w[(o-32)*64 + (c-64)]; }
      unsigned short hh, ll; split2(v, hh, ll);
      Wh[OFF_W2P + j] = hh; Wl[OFF_W2P + j] = ll;
    }
  }
  { int j = i - (NPT + 49152 + 128 + 8192); if (j >= 0 && j < 64) bias2c[j] = (j < 32) ? seg2_b[j] : dis2_b[j-32]; }
  { int j = i - (NPT + 49152 + 128 + 8192 + 64); if (j >= 0 && j < 129) g[j] = 0.f; }  // g + counter
  {
    int j = i - (NPT + 49152 + 128 + 8192 + 64 + 129);
    if (j >= 0 && j < NPT*32) {
      int n = j >> 5, ch = j & 31;
      float v = img[ch*HWIMG + choose[n]];
      feat[j] = v;
      unsigned short hh, ll; split2(v, hh, ll);
      feat_h[j] = hh; feat_l[j] = ll;
    }
  }
  {
    int j = i - (NPT + 49152 + 128 + 8192 + 64 + 129 + NPT*32);
    if (j >= 0 && j < OFF_W3) {
      float v;
      if      (j < OFF_CONV1)   v = pconv2_w[j];
      else if (j < OFF_CONV2)   v = conv1_w[j - OFF_CONV1];
      else if (j < OFF_PSCONV1) v = conv2_w[j - OFF_CONV2];
      else if (j < OFF_PSCONV2) v = psconv1_w[j - OFF_PSCONV1];
      else if (j < OFF_FINAL)   v = psconv2_w[j - OFF_PSCONV2];
      else                      v = final_w[j - OFF_FINAL];
      unsigned short hh, ll; split2(v, hh, ll);
      Wh[j] = hh; Wl[j] = ll;
    }
  }
}
#define PREP_TOTAL (NPT + 49152 + 128 + 8192 + 64 + 129 + NPT*32 + OFF_W3)

// ---------------- KNN (dot-form prune, exact select) + dis_center block --------
__device__ __forceinline__ unsigned long long bsort64(unsigned long long key, int lane) {
#pragma unroll
  for (int k = 2; k <= 64; k <<= 1) {
#pragma unroll
    for (int j = k >> 1; j > 0; j >>= 1) {
      unsigned long long o = __shfl_xor(key, j, 64);
      bool keepmin = (((lane & j) == 0) == ((lane & k) == 0));
      bool omin = o < key;
      key = (omin == keepmin) ? o : key;
    }
  }
  return key;
}
__device__ __forceinline__ unsigned long long bmerge64(unsigned long long key, int lane) {
#pragma unroll
  for (int j = 32; j > 0; j >>= 1) {
    unsigned long long o = __shfl_xor(key, j, 64);
    bool keepmin = ((lane & j) == 0);
    bool omin = o < key;
    key = (omin == keepmin) ? o : key;
  }
  return key;
}

__global__ __launch_bounds__(256) void k_knn(const float4* __restrict__ c4,
                                             int* __restrict__ idxo, float* __restrict__ wo,
                                             const float* __restrict__ cloud,
                                             const float* __restrict__ tvec,
                                             float* __restrict__ dc) {
  int tid = threadIdx.x, lane = tid & 63, wv = tid >> 6;
  if (blockIdx.x == NPT/4) {
    // ---- dis_center softmax (independent work folded in as one extra block) ----
    __shared__ float sred[4];
    float tx = tvec[0], ty = tvec[1], tz = tvec[2];
    float v[32];
    float m = -INFINITY;
#pragma unroll
    for (int i2 = 0; i2 < 32; ++i2) {
      int n = i2*256 + tid;
      float ax = cloud[n*3+0] + tx, ay = cloud[n*3+1] + ty, az = cloud[n*3+2] + tz;
      v[i2] = sqrtf(ax*ax + ay*ay + az*az);
      m = fmaxf(m, v[i2]);
    }
#pragma unroll
    for (int o = 1; o < 64; o <<= 1) m = fmaxf(m, __shfl_xor(m, o, 64));
    if (lane == 0) sred[wv] = m;
    __syncthreads();
    m = fmaxf(fmaxf(sred[0], sred[1]), fmaxf(sred[2], sred[3]));
    __syncthreads();
    float s = 0.f;
#pragma unroll
    for (int i2 = 0; i2 < 32; ++i2) { v[i2] = expf(v[i2] - m); s += v[i2]; }
#pragma unroll
    for (int o = 1; o < 64; o <<= 1) s += __shfl_xor(s, o, 64);
    if (lane == 0) sred[wv] = s;
    __syncthreads();
    s = sred[0] + sred[1] + sred[2] + sred[3];
#pragma unroll
    for (int i2 = 0; i2 < 32; ++i2) dc[i2*256 + tid] = v[i2] / s;
    return;
  }
  __shared__ float smin[4][256];
  __shared__ float sT[4];
  __shared__ float sd[4][KCAP];
  __shared__ int   sj[4][KCAP];
  __shared__ int   scnt[4];
  int q0 = blockIdx.x * 4;
  float4 p0 = c4[q0], p1 = c4[q0+1], p2 = c4[q0+2], p3 = c4[q0+3];
  float p0x = -2.f*p0.x, p0y = -2.f*p0.y, p0z = -2.f*p0.z;
  float p1x = -2.f*p1.x, p1y = -2.f*p1.y, p1z = -2.f*p1.z;
  float p2x = -2.f*p2.x, p2y = -2.f*p2.y, p2z = -2.f*p2.z;
  float p3x = -2.f*p3.x, p3y = -2.f*p3.y, p3z = -2.f*p3.z;
#define DDOT(PX,PY,PZ,PW,CJ) fmaf(PX,(CJ).x, fmaf(PY,(CJ).y, fmaf(PZ,(CJ).z, PW + (CJ).w)))
  float m0 = INFINITY, m1 = INFINITY, m2 = INFINITY, m3 = INFINITY;
  for (int t = 0; t < 32; ++t) {
    float4 cj = c4[t*256 + tid];
    m0 = fminf(m0, DDOT(p0x,p0y,p0z,p0.w,cj));
    m1 = fminf(m1, DDOT(p1x,p1y,p1z,p1.w,cj));
    m2 = fminf(m2, DDOT(p2x,p2y,p2z,p2.w,cj));
    m3 = fminf(m3, DDOT(p3x,p3y,p3z,p3.w,cj));
  }
  smin[0][tid] = m0; smin[1][tid] = m1; smin[2][tid] = m2; smin[3][tid] = m3;
  if (tid < 4) scnt[tid] = 0;
  __syncthreads();
  {
    float4 vv = *(const float4*)&smin[wv][lane*4];
    float v0 = vv.x, v1 = vv.y, v2 = vv.z, v3 = vv.w;
#define CSV(a,b) { if (b < a) { float t_ = a; a = b; b = t_; } }
    CSV(v0,v2) CSV(v1,v3) CSV(v0,v1) CSV(v2,v3) CSV(v1,v2)
    float T = 0.f;
    for (int it = 0; it < 32; ++it) {
      float mn = v0;
#pragma unroll
      for (int o = 1; o < 64; o <<= 1) mn = fminf(mn, __shfl_xor(mn, o, 64));
      T = mn;
      if (v0 == mn) { v0 = v1; v1 = v2; v2 = v3; v3 = INFINITY; }
    }
    if (lane == 0) sT[wv] = T * (1.f + 2e-5f) + 4e-5f;
  }
  __syncthreads();
  float T0 = sT[0], T1 = sT[1], T2 = sT[2], T3 = sT[3];
  for (int t = 0; t < 32; ++t) {
    int j = t*256 + tid;
    float4 cj = c4[j];
    float d;
#define APPEND(Q, P) { \
    float dx_ = (P).x-cj.x, dy_ = (P).y-cj.y, dz_ = (P).z-cj.z; \
    float de_ = dx_*dx_ + dy_*dy_ + dz_*dz_; \
    int p_ = atomicAdd(&scnt[Q],1); if (p_ < KCAP) { sd[Q][p_] = de_; sj[Q][p_] = j; } }
    d = DDOT(p0x,p0y,p0z,p0.w,cj); if (d <= T0) APPEND(0, p0);
    d = DDOT(p1x,p1y,p1z,p1.w,cj); if (d <= T1) APPEND(1, p1);
    d = DDOT(p2x,p2y,p2z,p2.w,cj); if (d <= T2) APPEND(2, p2);
    d = DDOT(p3x,p3y,p3z,p3.w,cj); if (d <= T3) APPEND(3, p3);
  }
  __syncthreads();
  int M = scnt[wv]; if (M > KCAP) M = KCAP;
  unsigned long long key = (lane < M)
      ? (((unsigned long long)__float_as_uint(sd[wv][lane]) << 32) | (unsigned)sj[wv][lane])
      : ~0ull;
  key = bsort64(key, lane);
  for (int base = 64; base < M; base += 64) {
    unsigned long long nk = (base + lane < M)
        ? (((unsigned long long)__float_as_uint(sd[wv][base+lane]) << 32) | (unsigned)sj[wv][base+lane])
        : ~0ull;
    nk = bsort64(nk, lane);
    nk = __shfl_xor(nk, 63, 64);
    key = key < nk ? key : nk;
    key = bmerge64(key, lane);
  }
  float dsel = __uint_as_float((unsigned)(key >> 32));
  int   jsel = (int)(unsigned)(key & 0xffffffffu);
  float v = -sqrtf(dsel);
  float mx = v;
#pragma unroll
  for (int o = 1; o < 32; o <<= 1) mx = fmaxf(mx, __shfl_xor(mx, o, 64));
  float e = expf(v - mx);
  float s = e;
#pragma unroll
  for (int o = 1; o < 32; o <<= 1) s += __shfl_xor(s, o, 64);
  if (lane < 32) {
    int q = q0 + wv;
    wo[q*32 + lane] = e / s;
    idxo[q*32 + lane] = jsel;
  }
}

// ---------------- fused MLP chains: 4 waves share one 16-row m-tile, t-split ---
// blocks [0,512): pconv1->pconv2->psconv1->psconv2 -> pf(f32), Yfp(f32)
// blocks [512,1024): conv1->conv2 -> Yf(f32)
__global__ __launch_bounds__(256) void k_chain(const float4* __restrict__ c4,
                                              const float* __restrict__ pconv1_w, const float* __restrict__ pconv1_b,
                                              const float* __restrict__ pconv2_b, const float* __restrict__ psconv1_b,
                                              const float* __restrict__ psconv2_b,
                                              const unsigned short* __restrict__ feat_h,
                                              const unsigned short* __restrict__ feat_l,
                                              const float* __restrict__ conv1_b, const float* __restrict__ conv2_b,
                                              const unsigned short* __restrict__ Wh,
                                              const unsigned short* __restrict__ Wl,
                                              float* __restrict__ pf, float* __restrict__ Yfp,
                                              float* __restrict__ Yf) {
  // LDS: slab1 @0 stride 136 (16x128) | slab2 @2176 stride 264 (16x256) | feat yh @0 stride 72
  __shared__ unsigned short sh_h[6400], sh_l[6400];
  int tid = threadIdx.x, lane = tid & 63, w = tid >> 6;
  int mr = lane & 15, q = lane >> 4;
  if (blockIdx.x < 512) {
    int m0 = blockIdx.x * 16;
    // ---- stage 1: pconv1 (K=3) in A-frag ownership (recomputed per wave) ----
    float4 cp = c4[m0 + mr];
    short8 ah0, al0, ah1, al1;
#pragma unroll
    for (int j = 0; j < 8; ++j) {
      int c0 = q*8 + j, c1 = 32 + q*8 + j;
      float v0 = lrelu(fmaf(cp.x, pconv1_w[c0*3+0], fmaf(cp.y, pconv1_w[c0*3+1],
                        fmaf(cp.z, pconv1_w[c0*3+2], pconv1_b[c0]))));
      float v1 = lrelu(fmaf(cp.x, pconv1_w[c1*3+0], fmaf(cp.y, pconv1_w[c1*3+1],
                        fmaf(cp.z, pconv1_w[c1*3+2], pconv1_b[c1]))));
      unsigned short hh, ll;
      split2(v0, hh, ll); ah0[j] = (short)hh; al0[j] = (short)ll;
      split2(v1, hh, ll); ah1[j] = (short)hh; al1[j] = (short)ll;
    }
    // ---- stage 2: pconv2 (K=64, N=128), wave w -> t {2w, 2w+1} ----
    f32x4 acc[2];
#pragma unroll
    for (int t = 0; t < 2; ++t) { f32x4 z = {0.f,0.f,0.f,0.f}; acc[t] = z; }
    const unsigned short* W2h = Wh + OFF_PCONV2;
    const unsigned short* W2l = Wl + OFF_PCONV2;
#pragma unroll
    for (int tt = 0; tt < 2; ++tt) {
      int wr = ((2*w+tt)*16 + mr)*64 + q*8;
      mfma3(acc[tt], ah0, al0, *(const short8*)(W2h + wr), *(const short8*)(W2l + wr));
      mfma3(acc[tt], ah1, al1, *(const short8*)(W2h + wr + 32), *(const short8*)(W2l + wr + 32));
    }
#pragma unroll
    for (int tt = 0; tt < 2; ++tt) {
      int n = (2*w+tt)*16 + mr;
      float b = pconv2_b[n];
#pragma unroll
      for (int r = 0; r < 4; ++r) {
        int row = q*4 + r;
        float v = acc[tt][r] + b;
        pf[(size_t)(m0+row)*128 + n] = v;
        unsigned short hh, ll; split2(v, hh, ll);
        sh_h[row*136 + n] = hh; sh_l[row*136 + n] = ll;
      }
    }
    __syncthreads();
    // ---- stage 3: psconv1 (K=128, N=256), wave w -> t {4w..4w+3} ----
    f32x4 acc2[4];
#pragma unroll
    for (int t = 0; t < 4; ++t) { f32x4 z = {0.f,0.f,0.f,0.f}; acc2[t] = z; }
    const unsigned short* W3h = Wh + OFF_PSCONV1;
    const unsigned short* W3l = Wl + OFF_PSCONV1;
#pragma unroll
    for (int ks = 0; ks < 4; ++ks) {
      short8 ah = *(const short8*)&sh_h[mr*136 + q*8 + ks*32];
      short8 al = *(const short8*)&sh_l[mr*136 + q*8 + ks*32];
#pragma unroll
      for (int tt = 0; tt < 4; ++tt) {
        int wr = ((4*w+tt)*16 + mr)*128 + q*8 + ks*32;
        mfma3(acc2[tt], ah, al, *(const short8*)(W3h + wr), *(const short8*)(W3l + wr));
      }
    }
#pragma unroll
    for (int tt = 0; tt < 4; ++tt) {
      int n = (4*w+tt)*16 + mr;
      float b = psconv1_b[n];
#pragma unroll
      for (int r = 0; r < 4; ++r) {
        int row = q*4 + r;
        float v = lrelu(acc2[tt][r] + b);
        unsigned short hh, ll; split2(v, hh, ll);
        sh_h[2176 + row*264 + n] = hh; sh_l[2176 + row*264 + n] = ll;
      }
    }
    __syncthreads();
    // ---- stage 4: psconv2 (K=256, N=128), wave w -> t {2w, 2w+1} -> Yfp ----
    f32x4 acc3[2];
#pragma unroll
    for (int t = 0; t < 2; ++t) { f32x4 z = {0.f,0.f,0.f,0.f}; acc3[t] = z; }
    const unsigned short* W4h = Wh + OFF_PSCONV2;
    const unsigned short* W4l = Wl + OFF_PSCONV2;
#pragma unroll
    for (int ks = 0; ks < 8; ++ks) {
      short8 ah = *(const short8*)&sh_h[2176 + mr*264 + q*8 + ks*32];
      short8 al = *(const short8*)&sh_l[2176 + mr*264 + q*8 + ks*32];
#pragma unroll
      for (int tt = 0; tt < 2; ++tt) {
        int wr = ((2*w+tt)*16 + mr)*256 + q*8 + ks*32;
        mfma3(acc3[tt], ah, al, *(const short8*)(W4h + wr), *(const short8*)(W4l + wr));
      }
    }
#pragma unroll
    for (int tt = 0; tt < 2; ++tt) {
      int n = (2*w+tt)*16 + mr;
      float b = psconv2_b[n];
#pragma unroll
      for (int r = 0; r < 4; ++r)
        Yfp[(size_t)(m0 + q*4 + r)*128 + n] = acc3[tt][r] + b;
    }
  } else {
    int m0 = (blockIdx.x - 512) * 16;
    // ---- conv1 (K=32, N=64), wave w -> t = w ----
    short8 ah = *(const short8*)(feat_h + (size_t)(m0+mr)*32 + q*8);
    short8 al = *(const short8*)(feat_l + (size_t)(m0+mr)*32 + q*8);
    f32x4 acc = {0.f,0.f,0.f,0.f};
    const unsigned short* W1h = Wh + OFF_CONV1;
    const unsigned short* W1l = Wl + OFF_CONV1;
    {
      int wr = (w*16 + mr)*32 + q*8;
      mfma3(acc, ah, al, *(const short8*)(W1h + wr), *(const short8*)(W1l + wr));
    }
    {
      int n = w*16 + mr;
      float b = conv1_b[n];
#pragma unroll
      for (int r = 0; r < 4; ++r) {
        int row = q*4 + r;
        float v = lrelu(acc[r] + b);
        unsigned short hh, ll; split2(v, hh, ll);
        sh_h[row*72 + n] = hh; sh_l[row*72 + n] = ll;
      }
    }
    __syncthreads();
    // ---- conv2 (K=64, N=128), wave w -> t {2w, 2w+1} -> Yf ----
    f32x4 acc2[2];
#pragma unroll
    for (int t = 0; t < 2; ++t) { f32x4 z = {0.f,0.f,0.f,0.f}; acc2[t] = z; }
    const unsigned short* W2h = Wh + OFF_CONV2;
    const unsigned short* W2l = Wl + OFF_CONV2;
#pragma unroll
    for (int ks = 0; ks < 2; ++ks) {
      short8 a2 = *(const short8*)&sh_h[mr*72 + q*8 + ks*32];
      short8 a2l = *(const short8*)&sh_l[mr*72 + q*8 + ks*32];
#pragma unroll
      for (int tt = 0; tt < 2; ++tt) {
        int wr = ((2*w+tt)*16 + mr)*64 + q*8 + ks*32;
        mfma3(acc2[tt], a2, a2l, *(const short8*)(W2h + wr), *(const short8*)(W2l + wr));
      }
    }
#pragma unroll
    for (int tt = 0; tt < 2; ++tt) {
      int n = (2*w+tt)*16 + mr;
      float b = conv2_b[n];
#pragma unroll
      for (int r = 0; r < 4; ++r)
        Yf[(size_t)(m0 + q*4 + r)*128 + n] = acc2[tt][r] + b;
    }
  }
}

// ---------------- pool: weighted max over 32 nbrs -> split-bf16 fin[416] ------
__global__ __launch_bounds__(256) void k_pool(const float* __restrict__ Yf,
                                              const float* __restrict__ Yfp,
                                              const float* __restrict__ feat,
                                              const float* __restrict__ pf,
                                              const int* __restrict__ idx,
                                              const float* __restrict__ w,
                                              unsigned short* __restrict__ finh,
                                              unsigned short* __restrict__ finl) {
  int n = blockIdx.x;
  int tid = threadIdx.x;
  __shared__ int sj[32];
  __shared__ float sw[32];
  if (tid < 32) { sj[tid] = idx[n*32+tid]; sw[tid] = w[n*32+tid]; }
  __syncthreads();
#define WRS(pos, val) { float v_ = (val); unsigned short h_, l_; split2(v_, h_, l_); \
    finh[(size_t)n*416 + (pos)] = h_; finl[(size_t)n*416 + (pos)] = l_; }
  if (tid < 128) {
    int c = tid;
    float acc = -INFINITY;
#pragma unroll 8
    for (int k = 0; k < 32; ++k) acc = fmaxf(acc, sw[k] * Yfp[(size_t)sj[k]*128 + c]);
    WRS(c, lrelu(acc));                       // fp  [0,128)
    WRS(288 + c, lrelu(pf[n*128 + c]));       // pf  [288,416)
    if (c < 32) WRS(128 + c, lrelu(feat[n*32 + c]));  // feat [128,160)
  } else {
    int c = tid - 128;
    float acc = -INFINITY;
#pragma unroll 8
    for (int k = 0; k < 32; ++k) acc = fmaxf(acc, sw[k] * Yf[(size_t)sj[k]*128 + c]);
    WRS(160 + c, lrelu(acc));                 // f   [160,288)
  }
}

// ---------------- final MFMA GEMM (K=416, N=128): 4 waves/m-tile, t-split -----
__global__ __launch_bounds__(256) void k_final(const unsigned short* __restrict__ Ah,
                                              const unsigned short* __restrict__ Al,
                                              const unsigned short* __restrict__ Wh,
                                              const unsigned short* __restrict__ Wl,
                                              const float* __restrict__ bias,
                                              float* __restrict__ Cf,
                                              unsigned short* __restrict__ Ch,
                                              unsigned short* __restrict__ Cl) {
  int tid = threadIdx.x, lane = tid & 63, w = tid >> 6;
  int mr = lane & 15, q = lane >> 4;
  int m0 = blockIdx.x * 16;
  f32x4 acc[2];
#pragma unroll
  for (int t = 0; t < 2; ++t) { f32x4 z = {0.f,0.f,0.f,0.f}; acc[t] = z; }
  const unsigned short* arh = Ah + (size_t)(m0 + mr) * 416 + q * 8;
  const unsigned short* arl = Al + (size_t)(m0 + mr) * 416 + q * 8;
#pragma unroll
  for (int ks = 0; ks < 13; ++ks) {
    short8 ah = *(const short8*)(arh + ks * 32);
    short8 al = *(const short8*)(arl + ks * 32);
#pragma unroll
    for (int tt = 0; tt < 2; ++tt) {
      int wr = ((2*w+tt)*16 + mr)*416 + q*8 + ks*32;
      mfma3(acc[tt], ah, al, *(const short8*)(Wh + wr), *(const short8*)(Wl + wr));
    }
  }
#pragma unroll
  for (int tt = 0; tt < 2; ++tt) {
    int n = (2*w+tt)*16 + mr;
    float b = bias[n];
#pragma unroll
    for (int r = 0; r < 4; ++r) {
      int row = m0 + q*4 + r;
      float v = acc[tt][r] + b;
      Cf[(size_t)row*128 + n] = v;
      unsigned short hh, ll; split2(v, hh, ll);
      Ch[(size_t)row*128 + n] = hh;
      Cl[(size_t)row*128 + n] = ll;
    }
  }
}

// ---------------- conv3 + head fused: 4 waves/m-tile, t-split -----------------
__global__ __launch_bounds__(256) void k_c3head(const unsigned short* __restrict__ Ah,
                                               const unsigned short* __restrict__ Al,
                                               const unsigned short* __restrict__ Wh,
                                               const unsigned short* __restrict__ Wl,
                                               const float* __restrict__ biasc,
                                               const float* __restrict__ bias2c,
                                               const float* __restrict__ segw, const float* __restrict__ segb,
                                               const float* __restrict__ disw, const float* __restrict__ disb,
                                               float* __restrict__ osegp, float* __restrict__ odisp) {
  __shared__ unsigned short t1h[2176], t1l[2176];
  __shared__ float shead[4][16][17];
  int tid = threadIdx.x, lane = tid & 63, w = tid >> 6;
  int mr = lane & 15, q = lane >> 4;
  int m0 = blockIdx.x * 16;
  // conv3 (K=384 via im2col taps, N=128: seg|dis), wave w -> t {2w, 2w+1}
  f32x4 acc[2];
#pragma unroll
  for (int t = 0; t < 2; ++t) { f32x4 z = {0.f,0.f,0.f,0.f}; acc[t] = z; }
  const unsigned short* W3h = Wh + OFF_W3;
  const unsigned short* W3l = Wl + OFF_W3;
#pragma unroll
  for (int ks = 0; ks < 12; ++ks) {
    int tap = ks >> 2;
    int kin = (ks & 3)*32 + q*8;
    int ar = m0 + mr + tap - 1;
    short8 ah = {0,0,0,0,0,0,0,0}, al = {0,0,0,0,0,0,0,0};
    if (ar >= 0 && ar < NPT) {
      ah = *(const short8*)(Ah + (size_t)ar*128 + kin);
      al = *(const short8*)(Al + (size_t)ar*128 + kin);
    }
#pragma unroll
    for (int tt = 0; tt < 2; ++tt) {
      int wr = ((2*w+tt)*16 + mr)*384 + ks*32 + q*8;
      mfma3(acc[tt], ah, al, *(const short8*)(W3h + wr), *(const short8*)(W3l + wr));
    }
  }
#pragma unroll
  for (int tt = 0; tt < 2; ++tt) {
    int n = (2*w+tt)*16 + mr;
    float b = biasc[n];
#pragma unroll
    for (int r = 0; r < 4; ++r) {
      int row = q*4 + r;
      float v = lrelu(acc[tt][r] + b);
      unsigned short hh, ll; split2(v, hh, ll);
      t1h[row*136 + n] = hh; t1l[row*136 + n] = ll;
    }
  }
  __syncthreads();
  // head GEMM (K=128, N=64 block-diag seg2|dis2), wave w -> head-t = w
  f32x4 acc2 = {0.f,0.f,0.f,0.f};
  const unsigned short* WPh = Wh + OFF_W2P;
  const unsigned short* WPl = Wl + OFF_W2P;
#pragma unroll
  for (int ks = 0; ks < 4; ++ks) {
    short8 ah = *(const short8*)&t1h[mr*136 + q*8 + ks*32];
    short8 al = *(const short8*)&t1l[mr*136 + q*8 + ks*32];
    int wr = (w*16 + mr)*128 + q*8 + ks*32;
    mfma3(acc2, ah, al, *(const short8*)(WPh + wr), *(const short8*)(WPl + wr));
  }
  float hw = (w < 2) ? segw[w*16 + mr] : disw[(w-2)*16 + mr];
  float bb = bias2c[w*16 + mr];
#pragma unroll
  for (int r = 0; r < 4; ++r)
    shead[w][q*4 + r][mr] = lrelu(acc2[r] + bb) * hw;
  __syncthreads();
  if (tid < 16) {
    float a = 0.f;
#pragma unroll
    for (int i = 0; i < 16; ++i) a += shead[0][tid][i] + shead[1][tid][i];
    osegp[m0 + tid] = a + segb[0];
  } else if (tid < 32) {
    float a = 0.f;
#pragma unroll
    for (int i = 0; i < 16; ++i) a += shead[2][tid-16][i] + shead[3][tid-16][i];
    odisp[m0 + tid - 16] = a + disb[0];
  }
}

// ---------------- g-reduction + keypoint MLP (counter-chained, one launch) ----
__global__ __launch_bounds__(256) void k_gkp(const float* __restrict__ fused,
                                             const float* __restrict__ dc,
                                             const float* __restrict__ seg,
                                             float* __restrict__ g,
                                             const float* __restrict__ l1w, const float* __restrict__ l1b,
                                             const float* __restrict__ l2w, const float* __restrict__ l2b,
                                             const float* __restrict__ l3w, const float* __restrict__ l3b,
                                             float* __restrict__ outp) {
  __shared__ float sbuf[256];
  __shared__ int slast;
  int tid = threadIdx.x;
  int c = tid & 127, h = tid >> 7;
  float acc = 0.f;
  for (int r = 0; r < 128; ++r) {
    int n = blockIdx.x*256 + r*2 + h;
    acc += fused[(size_t)n*128 + c] * dc[n] * seg[n];
  }
  sbuf[tid] = acc;
  __syncthreads();
  if (tid < 128) atomicAdd(&g[c], sbuf[tid] + sbuf[tid+128]);
  __threadfence();
  __syncthreads();
  if (tid == 0) slast = (atomicAdd((int*)(g + 128), 1) == 31);
  __syncthreads();
  if (!slast) return;
  __shared__ float sg[128], s1[90], s2[64];
  if (tid < 128) sg[tid] = atomicAdd(&g[tid], 0.f);
  __syncthreads();
  if (tid < 90) {
    float a = l1b[tid];
    for (int i = 0; i < 128; ++i) a += sg[i]*l1w[tid*128+i];
    s1[tid] = lrelu(a);
  }
  __syncthreads();
  if (tid < 64) {
    float a = l2b[tid];
    for (int i = 0; i < 90; ++i) a += s1[i]*l2w[tid*90+i];
    s2[tid] = lrelu(a);
  }
  __syncthreads();
  if (tid < 24) {
    float a = l3b[tid];
    for (int i = 0; i < 64; ++i) a += s2[i]*l3w[tid*64+i];
    outp[tid] = a;
  }
}

extern "C" void kernel_launch(void* const* d_in, const int* in_sizes, int n_in,
                              void* d_out, int out_size, void* d_ws, size_t ws_size,
                              hipStream_t stream) {
  const float* seg      = (const float*)d_in[0];
  const float* img      = (const float*)d_in[1];
  const float* cloud    = (const float*)d_in[2];
  const float* tvec     = (const float*)d_in[3];
  const int*   choose   = (const int*)d_in[4];
  const float* pconv1_w = (const float*)d_in[5];
  const float* pconv1_b = (const float*)d_in[6];
  const float* pconv2_w = (const float*)d_in[7];
  const float* pconv2_b = (const float*)d_in[8];
  const float* conv1_w  = (const float*)d_in[9];
  const float* conv1_b  = (const float*)d_in[10];
  const float* conv2_w  = (const float*)d_in[11];
  const float* conv2_b  = (const float*)d_in[12];
  const float* psconv1_w= (const float*)d_in[13];
  const float* psconv1_b= (const float*)d_in[14];
  const float* psconv2_w= (const float*)d_in[15];
  const float* psconv2_b= (const float*)d_in[16];
  const float* final_w  = (const float*)d_in[17];
  const float* final_b  = (const float*)d_in[18];
  const float* seg1_w   = (const float*)d_in[19];
  const float* seg1_b   = (const float*)d_in[20];
  const float* seg2_w   = (const float*)d_in[21];
  const float* seg2_b   = (const float*)d_in[22];
  const float* seg3_w   = (const float*)d_in[23];
  const float* seg3_b   = (const float*)d_in[24];
  const float* dis1_w   = (const float*)d_in[25];
  const float* dis1_b   = (const float*)d_in[26];
  const float* dis2_w   = (const float*)d_in[27];
  const float* dis2_b   = (const float*)d_in[28];
  const float* dis3_w   = (const float*)d_in[29];
  const float* dis3_b   = (const float*)d_in[30];
  const float* lin1_w   = (const float*)d_in[31];
  const float* lin1_b   = (const float*)d_in[32];
  const float* lin2_w   = (const float*)d_in[33];
  const float* lin2_b   = (const float*)d_in[34];
  const float* lin3_w   = (const float*)d_in[35];
  const float* lin3_b   = (const float*)d_in[36];

  float* out = (float*)d_out;
  float* ws  = (float*)d_ws;

  // workspace layout (float offsets), no aliasing
  float* c4     = ws + 0;          // 32768
  float* feat   = ws + 32768;      // 262144
  unsigned short* feat_h = (unsigned short*)(ws + 294912);   // 131072 f
  unsigned short* feat_l = (unsigned short*)(ws + 425984);   // 131072 f
  float* pf     = ws + 557056;     // 1048576
  float* Yf     = ws + 1605632;    // 1048576
  float* Yfp    = ws + 2654208;    // 1048576
  int*   idx    = (int*)(ws + 3702784);   // 262144
  float* wsm    = ws + 3964928;    // 262144
  unsigned short* finh  = (unsigned short*)(ws + 4227072);   // 1703936 f
  unsigned short* finl  = (unsigned short*)(ws + 5931008);   // 1703936 f
  float* fused  = ws + 7634944;    // 1048576
  unsigned short* fusedh = (unsigned short*)(ws + 8683520);  // 524288 f
  unsigned short* fusedl = (unsigned short*)(ws + 9207808);  // 524288 f
  unsigned short* Wh    = (unsigned short*)(ws + 9732096);   // 97280 f
  unsigned short* Wl    = (unsigned short*)(ws + 9829376);   // 97280 f
  float* biasc  = ws + 9926656;    // 128
  float* bias2c = ws + 9926784;    // 64
  float* g      = ws + 9926848;    // 129 (g[128] is the int counter)

  float* o_kp   = out;             // 24
  float* o_disp = out + 24;        // 8192
  float* o_dc   = out + 8216;      // 8192
  float* o_segp = out + 16408;     // 8192

  k_prep<<<(PREP_TOTAL + 255)/256, 256, 0, stream>>>(
      cloud, choose, img, seg1_w, dis1_w, seg1_b, dis1_b,
      seg2_w, dis2_w, seg2_b, dis2_b,
      pconv2_w, conv1_w, conv2_w, psconv1_w, psconv2_w, final_w,
      c4, biasc, bias2c, g, feat, feat_h, feat_l, Wh, Wl);

  k_knn<<<NPT/4 + 1, 256, 0, stream>>>((const float4*)c4, idx, wsm, cloud, tvec, o_dc);

  k_chain<<<1024, 256, 0, stream>>>(
      (const float4*)c4, pconv1_w, pconv1_b, pconv2_b, psconv1_b, psconv2_b,
      feat_h, feat_l, conv1_b, conv2_b, Wh, Wl, pf, Yfp, Yf);

  k_pool<<<NPT, 256, 0, stream>>>(Yf, Yfp, feat, pf, idx, wsm, finh, finl);

  k_final<<<512, 256, 0, stream>>>(finh, finl, Wh + OFF_FINAL, Wl + OFF_FINAL,
                                   final_b, fused, fusedh, fusedl);

  k_c3head<<<512, 256, 0, stream>>>(fusedh, fusedl, Wh, Wl, biasc, bias2c,
                                    seg3_w, seg3_b, dis3_w, dis3_b, o_segp, o_disp);

  k_gkp<<<32, 256, 0, stream>>>(fused, o_dc, seg, g,
                                lin1_w, lin1_b, lin2_w, lin2_b, lin3_w, lin3_b, o_kp);

  (void)in_sizes; (void)n_in; (void)out_size; (void)ws_size;
}